// Round 1
// baseline (1311.363 us; speedup 1.0000x reference)
//
#include <hip/hip_runtime.h>

#define NN 100000
#define NE 1600000
#define TN 16

static constexpr float BN_EPS = 1e-5f;
static constexpr float NORM_EPS = 1e-12f;

// ---------------- weight pre-transpose (W[j][k] -> Wt[k][j]) ----------------
struct TposeArgs {
    const float* src[10];
    float* dst[10];
    int rows[10];
};

__global__ void transpose_kernel(TposeArgs a) {
    const int m = blockIdx.x;
    const float* __restrict__ s = a.src[m];
    float* __restrict__ d = a.dst[m];
    const int J = a.rows[m];
    const int total = J * 128;
    for (int idx = threadIdx.x; idx < total; idx += 256) {
        const int j = idx >> 7;
        const int k = idx & 127;
        d[k * J + j] = s[idx];
    }
}

// ---------------- CSR build ----------------
__global__ void hist_kernel(const int* __restrict__ dst, int* __restrict__ cnt) {
    const int i = blockIdx.x * 256 + threadIdx.x;
    if (i < NE) atomicAdd(&cnt[dst[i]], 1);
}

__global__ void scan1_kernel(const int* __restrict__ cnt, int* __restrict__ pre,
                             int* __restrict__ blksum) {
    __shared__ int lds[256];
    const int tid = threadIdx.x;
    const int base = blockIdx.x * 1024 + tid * 4;
    const int v0 = (base + 0 < NN) ? cnt[base + 0] : 0;
    const int v1 = (base + 1 < NN) ? cnt[base + 1] : 0;
    const int v2 = (base + 2 < NN) ? cnt[base + 2] : 0;
    const int v3 = (base + 3 < NN) ? cnt[base + 3] : 0;
    const int tsum = v0 + v1 + v2 + v3;
    lds[tid] = tsum;
    __syncthreads();
    int val = tsum;
    for (int off = 1; off < 256; off <<= 1) {
        const int t = (tid >= off) ? lds[tid - off] : 0;
        __syncthreads();
        val += t;
        lds[tid] = val;
        __syncthreads();
    }
    const int excl = val - tsum;
    if (base + 0 < NN) pre[base + 0] = excl;
    if (base + 1 < NN) pre[base + 1] = excl + v0;
    if (base + 2 < NN) pre[base + 2] = excl + v0 + v1;
    if (base + 3 < NN) pre[base + 3] = excl + v0 + v1 + v2;
    if (tid == 255) blksum[blockIdx.x] = val;
}

__global__ void scan2_kernel(int* __restrict__ blksum, int nb) {
    __shared__ int lds[128];
    const int tid = threadIdx.x;
    const int v = (tid < nb) ? blksum[tid] : 0;
    lds[tid] = v;
    __syncthreads();
    int val = v;
    for (int off = 1; off < 128; off <<= 1) {
        const int t = (tid >= off) ? lds[tid - off] : 0;
        __syncthreads();
        val += t;
        lds[tid] = val;
        __syncthreads();
    }
    if (tid < nb) blksum[tid] = val - v;
}

__global__ void scan3_kernel(int* __restrict__ pre, const int* __restrict__ blksum,
                             const int* __restrict__ cnt, float* __restrict__ inv_deg) {
    const int i = blockIdx.x * 256 + threadIdx.x;
    if (i < NN) {
        pre[i] += blksum[i >> 10];
        const int c = cnt[i];
        inv_deg[i] = 1.0f / (float)(c < 1 ? 1 : c);
    }
    if (i == 0) pre[NN] = NE;
}

__global__ void fill_kernel(const int* __restrict__ src, const int* __restrict__ dst,
                            const int* __restrict__ row_ptr, int* __restrict__ fill_cnt,
                            int* __restrict__ csr_src) {
    const int i = blockIdx.x * 256 + threadIdx.x;
    if (i < NE) {
        const int d = dst[i];
        const int pos = row_ptr[d] + atomicAdd(&fill_cnt[d], 1);
        csr_src[pos] = src[i];
    }
}

// ---------------- encoder: h = relu(x @ W^T + b), 128x128 ----------------
__global__ __launch_bounds__(256, 2)
void encoder_kernel(const float* __restrict__ x, float* __restrict__ h_out,
                    const float* __restrict__ wt, const float* __restrict__ bias) {
    __shared__ float sW[128 * 128];
    __shared__ float sRows[TN * 128];
    const int tid = threadIdx.x;
    const int nb = blockIdx.x * TN;

    {
        const float4* s = (const float4*)(x + nb * 128);
        float4* d = (float4*)sRows;
        d[tid] = s[tid];
        d[tid + 256] = s[tid + 256];
        const float4* ws_ = (const float4*)wt;
        float4* wd = (float4*)sW;
        #pragma unroll
        for (int i = 0; i < 16; ++i) wd[tid + i * 256] = ws_[tid + i * 256];
    }
    __syncthreads();

    const int j4 = (tid & 31) * 4;
    const int ng = tid >> 5;
    float4 a0 = {0, 0, 0, 0}, a1 = {0, 0, 0, 0};
    #pragma unroll 8
    for (int k = 0; k < 128; ++k) {
        const float4 w = *(const float4*)(sW + k * 128 + j4);
        const float r0 = sRows[ng * 128 + k];
        const float r1 = sRows[(ng + 8) * 128 + k];
        a0.x += r0 * w.x; a0.y += r0 * w.y; a0.z += r0 * w.z; a0.w += r0 * w.w;
        a1.x += r1 * w.x; a1.y += r1 * w.y; a1.z += r1 * w.z; a1.w += r1 * w.w;
    }
    const float4 b = *(const float4*)(bias + j4);
    float4 o0, o1;
    o0.x = fmaxf(a0.x + b.x, 0.f); o0.y = fmaxf(a0.y + b.y, 0.f);
    o0.z = fmaxf(a0.z + b.z, 0.f); o0.w = fmaxf(a0.w + b.w, 0.f);
    o1.x = fmaxf(a1.x + b.x, 0.f); o1.y = fmaxf(a1.y + b.y, 0.f);
    o1.z = fmaxf(a1.z + b.z, 0.f); o1.w = fmaxf(a1.w + b.w, 0.f);
    *(float4*)(h_out + (nb + ng) * 128 + j4) = o0;
    *(float4*)(h_out + (nb + ng + 8) * 128 + j4) = o1;
}

// ---------------- fused SAGE layer ----------------
__global__ __launch_bounds__(256, 2)
void sage_layer_kernel(const float* __restrict__ h_in, float* __restrict__ h_out,
                       const float* __restrict__ wl_t, const float* __restrict__ bl,
                       const float* __restrict__ wr_t,
                       const float* __restrict__ bn_g, const float* __restrict__ bn_b,
                       const float* __restrict__ bn_m, const float* __restrict__ bn_v,
                       const int* __restrict__ row_ptr, const int* __restrict__ csr_src,
                       const float* __restrict__ inv_deg) {
    __shared__ float sW[128 * 128];
    __shared__ float sMean[TN * 128];
    __shared__ float sRows[TN * 128];
    const int tid = threadIdx.x;
    const int nb = blockIdx.x * TN;

    // stage h tile + Wl
    {
        const float4* s = (const float4*)(h_in + nb * 128);
        float4* d = (float4*)sRows;
        d[tid] = s[tid];
        d[tid + 256] = s[tid + 256];
        const float4* ws_ = (const float4*)wl_t;
        float4* wd = (float4*)sW;
        #pragma unroll
        for (int i = 0; i < 16; ++i) wd[tid + i * 256] = ws_[tid + i * 256];
    }
    // gather neighbor mean: 16 threads per node
    {
        const int g = tid >> 4;
        const int t = (tid & 15) * 8;
        const int n = nb + g;
        float4 s0 = {0, 0, 0, 0}, s1 = {0, 0, 0, 0};
        const int rp0 = row_ptr[n], rp1 = row_ptr[n + 1];
        for (int e = rp0; e < rp1; ++e) {
            const int sidx = csr_src[e];
            const float4 v0 = *(const float4*)(h_in + sidx * 128 + t);
            const float4 v1 = *(const float4*)(h_in + sidx * 128 + t + 4);
            s0.x += v0.x; s0.y += v0.y; s0.z += v0.z; s0.w += v0.w;
            s1.x += v1.x; s1.y += v1.y; s1.z += v1.z; s1.w += v1.w;
        }
        const float id = inv_deg[n];
        float* m = sMean + g * 128 + t;
        m[0] = s0.x * id; m[1] = s0.y * id; m[2] = s0.z * id; m[3] = s0.w * id;
        m[4] = s1.x * id; m[5] = s1.y * id; m[6] = s1.z * id; m[7] = s1.w * id;
    }
    __syncthreads();

    const int j4 = (tid & 31) * 4;
    const int ng = tid >> 5;
    float4 a0 = {0, 0, 0, 0}, a1 = {0, 0, 0, 0};
    // pass 1: mean @ Wl^T
    #pragma unroll 8
    for (int k = 0; k < 128; ++k) {
        const float4 w = *(const float4*)(sW + k * 128 + j4);
        const float m0 = sMean[ng * 128 + k];
        const float m1 = sMean[(ng + 8) * 128 + k];
        a0.x += m0 * w.x; a0.y += m0 * w.y; a0.z += m0 * w.z; a0.w += m0 * w.w;
        a1.x += m1 * w.x; a1.y += m1 * w.y; a1.z += m1 * w.z; a1.w += m1 * w.w;
    }
    __syncthreads();
    // restage Wr
    {
        const float4* ws_ = (const float4*)wr_t;
        float4* wd = (float4*)sW;
        #pragma unroll
        for (int i = 0; i < 16; ++i) wd[tid + i * 256] = ws_[tid + i * 256];
    }
    __syncthreads();
    // pass 2: h @ Wr^T
    #pragma unroll 8
    for (int k = 0; k < 128; ++k) {
        const float4 w = *(const float4*)(sW + k * 128 + j4);
        const float r0 = sRows[ng * 128 + k];
        const float r1 = sRows[(ng + 8) * 128 + k];
        a0.x += r0 * w.x; a0.y += r0 * w.y; a0.z += r0 * w.z; a0.w += r0 * w.w;
        a1.x += r1 * w.x; a1.y += r1 * w.y; a1.z += r1 * w.z; a1.w += r1 * w.w;
    }

    // epilogue: +bias, L2 normalize, BN(eval), relu
    const float4 b = *(const float4*)(bl + j4);
    a0.x += b.x; a0.y += b.y; a0.z += b.z; a0.w += b.w;
    a1.x += b.x; a1.y += b.y; a1.z += b.z; a1.w += b.w;
    float ss0 = a0.x * a0.x + a0.y * a0.y + a0.z * a0.z + a0.w * a0.w;
    float ss1 = a1.x * a1.x + a1.y * a1.y + a1.z * a1.z + a1.w * a1.w;
    #pragma unroll
    for (int m = 16; m >= 1; m >>= 1) {
        ss0 += __shfl_xor(ss0, m);
        ss1 += __shfl_xor(ss1, m);
    }
    const float i0 = 1.0f / fmaxf(sqrtf(ss0), NORM_EPS);
    const float i1 = 1.0f / fmaxf(sqrtf(ss1), NORM_EPS);
    const float4 g = *(const float4*)(bn_g + j4);
    const float4 bb = *(const float4*)(bn_b + j4);
    const float4 mm = *(const float4*)(bn_m + j4);
    const float4 vv = *(const float4*)(bn_v + j4);
    float4 sc;
    sc.x = g.x * rsqrtf(vv.x + BN_EPS);
    sc.y = g.y * rsqrtf(vv.y + BN_EPS);
    sc.z = g.z * rsqrtf(vv.z + BN_EPS);
    sc.w = g.w * rsqrtf(vv.w + BN_EPS);
    float4 o0, o1;
    o0.x = fmaxf((a0.x * i0 - mm.x) * sc.x + bb.x, 0.f);
    o0.y = fmaxf((a0.y * i0 - mm.y) * sc.y + bb.y, 0.f);
    o0.z = fmaxf((a0.z * i0 - mm.z) * sc.z + bb.z, 0.f);
    o0.w = fmaxf((a0.w * i0 - mm.w) * sc.w + bb.w, 0.f);
    o1.x = fmaxf((a1.x * i1 - mm.x) * sc.x + bb.x, 0.f);
    o1.y = fmaxf((a1.y * i1 - mm.y) * sc.y + bb.y, 0.f);
    o1.z = fmaxf((a1.z * i1 - mm.z) * sc.z + bb.z, 0.f);
    o1.w = fmaxf((a1.w * i1 - mm.w) * sc.w + bb.w, 0.f);
    *(float4*)(h_out + (nb + ng) * 128 + j4) = o0;
    *(float4*)(h_out + (nb + ng + 8) * 128 + j4) = o1;
}

// ---------------- fused 3-head readout ----------------
__global__ __launch_bounds__(256, 2)
void heads_kernel(const float* __restrict__ h,
                  const float* __restrict__ wt1, const float* __restrict__ b1,
                  const float* __restrict__ w2, const float* __restrict__ b2,
                  const float* __restrict__ wtc, const float* __restrict__ cb1,
                  const float* __restrict__ cw2, const float* __restrict__ cb2,
                  const float* __restrict__ wtb, const float* __restrict__ bb1,
                  const float* __restrict__ bw2, const float* __restrict__ bb2,
                  float* __restrict__ o_order, float* __restrict__ o_cost,
                  float* __restrict__ o_bw) {
    __shared__ float sW[128 * 128];
    __shared__ float sRows[TN * 128];
    const int tid = threadIdx.x;
    const int nb = blockIdx.x * TN;

    {
        const float4* s = (const float4*)(h + nb * 128);
        float4* d = (float4*)sRows;
        d[tid] = s[tid];
        d[tid + 256] = s[tid + 256];
        const float4* ws_ = (const float4*)wt1;
        float4* wd = (float4*)sW;
        #pragma unroll
        for (int i = 0; i < 16; ++i) wd[tid + i * 256] = ws_[tid + i * 256];
    }
    __syncthreads();

    // pass 1: order head (hidden 128)
    {
        const int j4 = (tid & 31) * 4;
        const int ng = tid >> 5;
        float4 a0 = {0, 0, 0, 0}, a1 = {0, 0, 0, 0};
        #pragma unroll 8
        for (int k = 0; k < 128; ++k) {
            const float4 w = *(const float4*)(sW + k * 128 + j4);
            const float r0 = sRows[ng * 128 + k];
            const float r1 = sRows[(ng + 8) * 128 + k];
            a0.x += r0 * w.x; a0.y += r0 * w.y; a0.z += r0 * w.z; a0.w += r0 * w.w;
            a1.x += r1 * w.x; a1.y += r1 * w.y; a1.z += r1 * w.z; a1.w += r1 * w.w;
        }
        const float4 b = *(const float4*)(b1 + j4);
        const float4 wv = *(const float4*)(w2 + j4);
        float po0 = fmaxf(a0.x + b.x, 0.f) * wv.x + fmaxf(a0.y + b.y, 0.f) * wv.y
                  + fmaxf(a0.z + b.z, 0.f) * wv.z + fmaxf(a0.w + b.w, 0.f) * wv.w;
        float po1 = fmaxf(a1.x + b.x, 0.f) * wv.x + fmaxf(a1.y + b.y, 0.f) * wv.y
                  + fmaxf(a1.z + b.z, 0.f) * wv.z + fmaxf(a1.w + b.w, 0.f) * wv.w;
        #pragma unroll
        for (int m = 16; m >= 1; m >>= 1) {
            po0 += __shfl_xor(po0, m);
            po1 += __shfl_xor(po1, m);
        }
        if ((tid & 31) == 0) {
            const float bconst = b2[0];
            o_order[nb + ng] = po0 + bconst;
            o_order[nb + ng + 8] = po1 + bconst;
        }
    }

    // pass 2 & 3: cost / bullwhip heads (hidden 64)
    const float* wts[2] = {wtc, wtb};
    const float* h1b[2] = {cb1, bb1};
    const float* h2w[2] = {cw2, bw2};
    const float* h2b[2] = {cb2, bb2};
    float* outs[2] = {o_cost, o_bw};
    #pragma unroll
    for (int p = 0; p < 2; ++p) {
        __syncthreads();
        {
            const float4* ws_ = (const float4*)wts[p];
            float4* wd = (float4*)sW;
            #pragma unroll
            for (int i = 0; i < 8; ++i) wd[tid + i * 256] = ws_[tid + i * 256];
        }
        __syncthreads();
        const int j4 = (tid & 15) * 4;
        const int n = tid >> 4;
        float4 a = {0, 0, 0, 0};
        #pragma unroll 8
        for (int k = 0; k < 128; ++k) {
            const float4 w = *(const float4*)(sW + k * 64 + j4);
            const float r = sRows[n * 128 + k];
            a.x += r * w.x; a.y += r * w.y; a.z += r * w.z; a.w += r * w.w;
        }
        const float4 b = *(const float4*)(h1b[p] + j4);
        const float4 wv = *(const float4*)(h2w[p] + j4);
        float po = fmaxf(a.x + b.x, 0.f) * wv.x + fmaxf(a.y + b.y, 0.f) * wv.y
                 + fmaxf(a.z + b.z, 0.f) * wv.z + fmaxf(a.w + b.w, 0.f) * wv.w;
        #pragma unroll
        for (int m = 8; m >= 1; m >>= 1) po += __shfl_xor(po, m);
        if ((tid & 15) == 0) outs[p][nb + n] = po + h2b[p][0];
    }
}

extern "C" void kernel_launch(void* const* d_in, const int* in_sizes, int n_in,
                              void* d_out, int out_size, void* d_ws, size_t ws_size,
                              hipStream_t stream) {
    (void)in_sizes; (void)n_in; (void)out_size;

    const float* x       = (const float*)d_in[0];
    const int*   ei      = (const int*)d_in[1];
    const float* enc_w   = (const float*)d_in[2];
    const float* enc_b   = (const float*)d_in[3];
    const float* ll_w    = (const float*)d_in[4];
    const float* ll_b    = (const float*)d_in[5];
    const float* lr_w    = (const float*)d_in[6];
    const float* bn_g    = (const float*)d_in[7];
    const float* bn_b    = (const float*)d_in[8];
    const float* bn_m    = (const float*)d_in[9];
    const float* bn_v    = (const float*)d_in[10];
    const float* out_w1  = (const float*)d_in[11];
    const float* out_b1  = (const float*)d_in[12];
    const float* out_w2  = (const float*)d_in[13];
    const float* out_b2  = (const float*)d_in[14];
    const float* cost_w1 = (const float*)d_in[15];
    const float* cost_b1 = (const float*)d_in[16];
    const float* cost_w2 = (const float*)d_in[17];
    const float* cost_b2 = (const float*)d_in[18];
    const float* bw_w1   = (const float*)d_in[19];
    const float* bw_b1   = (const float*)d_in[20];
    const float* bw_w2   = (const float*)d_in[21];
    const float* bw_b2   = (const float*)d_in[22];

    const int* e_src = ei;
    const int* e_dst = ei + NE;

    float* o_order = (float*)d_out;
    float* o_cost  = o_order + NN;
    float* o_bw    = o_cost + NN;
    float* o_h     = o_bw + NN;   // N*128 floats

    // workspace layout (4-byte units)
    float* ws      = (float*)d_ws;
    float* hA      = ws;                         // 12.8M floats
    float* hB      = hA + NN * 128;              // 12.8M floats
    float* wt      = hB + NN * 128;              // 147456 floats
    float* wt_enc  = wt;
    float* wt_ll   = wt + 16384;                 // 3 x [128][128]
    float* wt_lr   = wt + 16384 * 4;             // 3 x [128][128]
    float* wt_out1 = wt + 16384 * 7;
    float* wt_c1   = wt + 16384 * 8;             // [128][64]
    float* wt_bw1  = wt + 16384 * 8 + 8192;      // [128][64]
    int*   cnt      = (int*)(wt + 147456);
    int*   fill_cnt = cnt + NN;
    int*   row_ptr  = fill_cnt + NN;             // NN+1 ints
    float* inv_deg  = (float*)(row_ptr + NN + 4);
    int*   csr_src  = (int*)(inv_deg + NN);
    int*   blksum   = csr_src + NE;              // 98 ints

    const size_t need = (size_t)(csr_src + NE + 128 - (int*)d_ws) * 4;
    if (ws_size < need) return;  // insufficient scratch; bail cleanly

    // zero histogram + fill counters (adjacent -> one memset)
    hipMemsetAsync(cnt, 0, 2 * NN * sizeof(int), stream);

    // pre-transpose all GEMM weights
    TposeArgs ta;
    ta.src[0] = enc_w;          ta.dst[0] = wt_enc;          ta.rows[0] = 128;
    ta.src[1] = ll_w;           ta.dst[1] = wt_ll;           ta.rows[1] = 128;
    ta.src[2] = ll_w + 16384;   ta.dst[2] = wt_ll + 16384;   ta.rows[2] = 128;
    ta.src[3] = ll_w + 32768;   ta.dst[3] = wt_ll + 32768;   ta.rows[3] = 128;
    ta.src[4] = lr_w;           ta.dst[4] = wt_lr;           ta.rows[4] = 128;
    ta.src[5] = lr_w + 16384;   ta.dst[5] = wt_lr + 16384;   ta.rows[5] = 128;
    ta.src[6] = lr_w + 32768;   ta.dst[6] = wt_lr + 32768;   ta.rows[6] = 128;
    ta.src[7] = out_w1;         ta.dst[7] = wt_out1;         ta.rows[7] = 128;
    ta.src[8] = cost_w1;        ta.dst[8] = wt_c1;           ta.rows[8] = 64;
    ta.src[9] = bw_w1;          ta.dst[9] = wt_bw1;          ta.rows[9] = 64;
    transpose_kernel<<<10, 256, 0, stream>>>(ta);

    // CSR build
    hist_kernel<<<(NE + 255) / 256, 256, 0, stream>>>(e_dst, cnt);
    const int nblk = (NN + 1023) / 1024;
    scan1_kernel<<<nblk, 256, 0, stream>>>(cnt, row_ptr, blksum);
    scan2_kernel<<<1, 128, 0, stream>>>(blksum, nblk);
    scan3_kernel<<<(NN + 255) / 256, 256, 0, stream>>>(row_ptr, blksum, cnt, inv_deg);
    fill_kernel<<<(NE + 255) / 256, 256, 0, stream>>>(e_src, e_dst, row_ptr, fill_cnt, csr_src);

    // forward pass
    encoder_kernel<<<NN / TN, 256, 0, stream>>>(x, hA, wt_enc, enc_b);
    sage_layer_kernel<<<NN / TN, 256, 0, stream>>>(hA, hB, wt_ll, ll_b, wt_lr,
        bn_g, bn_b, bn_m, bn_v, row_ptr, csr_src, inv_deg);
    sage_layer_kernel<<<NN / TN, 256, 0, stream>>>(hB, hA, wt_ll + 16384, ll_b + 128, wt_lr + 16384,
        bn_g + 128, bn_b + 128, bn_m + 128, bn_v + 128, row_ptr, csr_src, inv_deg);
    sage_layer_kernel<<<NN / TN, 256, 0, stream>>>(hA, o_h, wt_ll + 32768, ll_b + 256, wt_lr + 32768,
        bn_g + 256, bn_b + 256, bn_m + 256, bn_v + 256, row_ptr, csr_src, inv_deg);
    heads_kernel<<<NN / TN, 256, 0, stream>>>(o_h, wt_out1, out_b1, out_w2, out_b2,
        wt_c1, cost_b1, cost_w2, cost_b2, wt_bw1, bw_b1, bw_w2, bw_b2,
        o_order, o_cost, o_bw);
}

// Round 2
// 969.790 us; speedup vs baseline: 1.3522x; 1.3522x over previous
//
#include <hip/hip_runtime.h>

#define NN 100000
#define NE 1600000
#define TN 16

static constexpr float BN_EPS = 1e-5f;
static constexpr float NORM_EPS = 1e-12f;

typedef unsigned int u32;
typedef unsigned short u16;

// ---------------- bf16 helpers (bit ops, RTN pack) ----------------
__device__ __forceinline__ float bflo(u32 u) {
    u32 v = u << 16; float f; __builtin_memcpy(&f, &v, 4); return f;
}
__device__ __forceinline__ float bfhi(u32 u) {
    u32 v = u & 0xffff0000u; float f; __builtin_memcpy(&f, &v, 4); return f;
}
__device__ __forceinline__ u32 packbf(float a, float b) {
    u32 ua, ub; __builtin_memcpy(&ua, &a, 4); __builtin_memcpy(&ub, &b, 4);
    u32 ra = (ua + 0x7fffu + ((ua >> 16) & 1u)) >> 16;
    u32 rb = (ub + 0x7fffu + ((ub >> 16) & 1u)) & 0xffff0000u;
    return ra | rb;
}
__device__ __forceinline__ u16 f2bf(float a) {
    u32 ua; __builtin_memcpy(&ua, &a, 4);
    return (u16)((ua + 0x7fffu + ((ua >> 16) & 1u)) >> 16);
}
__device__ __forceinline__ float4 cvt4(uint2 w) {
    return make_float4(bflo(w.x), bfhi(w.x), bflo(w.y), bfhi(w.y));
}
__device__ __forceinline__ void acc8(float* s, uint4 v) {
    s[0] += bflo(v.x); s[1] += bfhi(v.x);
    s[2] += bflo(v.y); s[3] += bfhi(v.y);
    s[4] += bflo(v.z); s[5] += bfhi(v.z);
    s[6] += bflo(v.w); s[7] += bfhi(v.w);
}

// ---------------- weight pre-transpose + bf16 cast (W[j][k] -> Wt[k][j]) ----
struct TposeArgs {
    const float* src[10];
    u16* dst[10];
    int rows[10];
};

__global__ void transpose_kernel(TposeArgs a) {
    const int m = blockIdx.x;
    const float* __restrict__ s = a.src[m];
    u16* __restrict__ d = a.dst[m];
    const int J = a.rows[m];
    const int total = J * 128;
    for (int idx = threadIdx.x; idx < total; idx += 256) {
        const int j = idx >> 7;
        const int k = idx & 127;
        d[k * J + j] = f2bf(s[idx]);
    }
}

// ---------------- CSR build ----------------
__global__ void hist_kernel(const int* __restrict__ dst, int* __restrict__ cnt) {
    const int i = blockIdx.x * 256 + threadIdx.x;
    if (i < NE) atomicAdd(&cnt[dst[i]], 1);
}

__global__ void scan1_kernel(const int* __restrict__ cnt, int* __restrict__ pre,
                             int* __restrict__ blksum) {
    __shared__ int lds[256];
    const int tid = threadIdx.x;
    const int base = blockIdx.x * 1024 + tid * 4;
    const int v0 = (base + 0 < NN) ? cnt[base + 0] : 0;
    const int v1 = (base + 1 < NN) ? cnt[base + 1] : 0;
    const int v2 = (base + 2 < NN) ? cnt[base + 2] : 0;
    const int v3 = (base + 3 < NN) ? cnt[base + 3] : 0;
    const int tsum = v0 + v1 + v2 + v3;
    lds[tid] = tsum;
    __syncthreads();
    int val = tsum;
    for (int off = 1; off < 256; off <<= 1) {
        const int t = (tid >= off) ? lds[tid - off] : 0;
        __syncthreads();
        val += t;
        lds[tid] = val;
        __syncthreads();
    }
    const int excl = val - tsum;
    if (base + 0 < NN) pre[base + 0] = excl;
    if (base + 1 < NN) pre[base + 1] = excl + v0;
    if (base + 2 < NN) pre[base + 2] = excl + v0 + v1;
    if (base + 3 < NN) pre[base + 3] = excl + v0 + v1 + v2;
    if (tid == 255) blksum[blockIdx.x] = val;
}

__global__ void scan2_kernel(int* __restrict__ blksum, int nb) {
    __shared__ int lds[128];
    const int tid = threadIdx.x;
    const int v = (tid < nb) ? blksum[tid] : 0;
    lds[tid] = v;
    __syncthreads();
    int val = v;
    for (int off = 1; off < 128; off <<= 1) {
        const int t = (tid >= off) ? lds[tid - off] : 0;
        __syncthreads();
        val += t;
        lds[tid] = val;
        __syncthreads();
    }
    if (tid < nb) blksum[tid] = val - v;
}

__global__ void scan3_kernel(int* __restrict__ pre, const int* __restrict__ blksum,
                             const int* __restrict__ cnt, float* __restrict__ inv_deg) {
    const int i = blockIdx.x * 256 + threadIdx.x;
    if (i < NN) {
        pre[i] += blksum[i >> 10];
        const int c = cnt[i];
        inv_deg[i] = 1.0f / (float)(c < 1 ? 1 : c);
    }
    if (i == 0) pre[NN] = NE;
}

__global__ void fill_kernel(const int* __restrict__ src, const int* __restrict__ dst,
                            const int* __restrict__ row_ptr, int* __restrict__ fill_cnt,
                            int* __restrict__ csr_src) {
    const int i = blockIdx.x * 256 + threadIdx.x;
    if (i < NE) {
        const int d = dst[i];
        const int pos = row_ptr[d] + atomicAdd(&fill_cnt[d], 1);
        csr_src[pos] = src[i];
    }
}

// ---------------- encoder: h = relu(x @ W^T + b), bf16 out ----------------
__global__ __launch_bounds__(256, 4)
void encoder_kernel(const float* __restrict__ x, u16* __restrict__ h_out,
                    const u16* __restrict__ wt, const float* __restrict__ bias) {
    __shared__ u32 sW[128 * 64];       // bf16 [k][j], 32 KB
    __shared__ float sRows[TN * 128];  // 8 KB
    const int tid = threadIdx.x;
    const int nb = blockIdx.x * TN;

    {
        const float4* s = (const float4*)(x + (size_t)nb * 128);
        float4* d = (float4*)sRows;
        d[tid] = s[tid];
        d[tid + 256] = s[tid + 256];
        const uint4* ws_ = (const uint4*)wt;
        uint4* wd = (uint4*)sW;
        #pragma unroll
        for (int i = 0; i < 8; ++i) wd[tid + i * 256] = ws_[tid + i * 256];
    }
    __syncthreads();

    const int j4 = (tid & 31) * 4;
    const int ng = tid >> 5;
    float4 a0 = {0, 0, 0, 0}, a1 = {0, 0, 0, 0};
    #pragma unroll 4
    for (int k = 0; k < 128; k += 2) {
        const uint2 w0 = *(const uint2*)&sW[k * 64 + (j4 >> 1)];
        const uint2 w1 = *(const uint2*)&sW[(k + 1) * 64 + (j4 >> 1)];
        const float4 wa = cvt4(w0), wb = cvt4(w1);
        const float r00 = sRows[ng * 128 + k],       r01 = sRows[ng * 128 + k + 1];
        const float r10 = sRows[(ng + 8) * 128 + k], r11 = sRows[(ng + 8) * 128 + k + 1];
        a0.x += r00 * wa.x + r01 * wb.x; a0.y += r00 * wa.y + r01 * wb.y;
        a0.z += r00 * wa.z + r01 * wb.z; a0.w += r00 * wa.w + r01 * wb.w;
        a1.x += r10 * wa.x + r11 * wb.x; a1.y += r10 * wa.y + r11 * wb.y;
        a1.z += r10 * wa.z + r11 * wb.z; a1.w += r10 * wa.w + r11 * wb.w;
    }
    const float4 b = *(const float4*)(bias + j4);
    uint2 p0, p1;
    p0.x = packbf(fmaxf(a0.x + b.x, 0.f), fmaxf(a0.y + b.y, 0.f));
    p0.y = packbf(fmaxf(a0.z + b.z, 0.f), fmaxf(a0.w + b.w, 0.f));
    p1.x = packbf(fmaxf(a1.x + b.x, 0.f), fmaxf(a1.y + b.y, 0.f));
    p1.y = packbf(fmaxf(a1.z + b.z, 0.f), fmaxf(a1.w + b.w, 0.f));
    *(uint2*)(h_out + (size_t)(nb + ng) * 128 + j4) = p0;
    *(uint2*)(h_out + (size_t)(nb + ng + 8) * 128 + j4) = p1;
}

// ---------------- fused SAGE layer (bf16 in, bf16/f32 out) ----------------
template<int LAST>
__global__ __launch_bounds__(256, 4)
void sage_layer_kernel(const u16* __restrict__ h_in,
                       u16* __restrict__ h_out_bf, float* __restrict__ h_out_f,
                       const u16* __restrict__ wl_t, const float* __restrict__ bl,
                       const u16* __restrict__ wr_t,
                       const float* __restrict__ bn_g, const float* __restrict__ bn_b,
                       const float* __restrict__ bn_m, const float* __restrict__ bn_v,
                       const int* __restrict__ row_ptr, const int* __restrict__ csr_src,
                       const float* __restrict__ inv_deg) {
    __shared__ u32 sW[128 * 64];     // 32 KB bf16 weights
    __shared__ u32 sMean[TN * 64];   // 4 KB bf16 means
    __shared__ u32 sRowsB[TN * 64];  // 4 KB bf16 rows
    const int tid = threadIdx.x;
    const int nb = blockIdx.x * TN;

    // stage h rows (bf16 passthrough) + Wl
    ((uint4*)sRowsB)[tid] = ((const uint4*)(h_in + (size_t)nb * 128))[tid];
    {
        const uint4* ws_ = (const uint4*)wl_t;
        uint4* wd = (uint4*)sW;
        #pragma unroll
        for (int i = 0; i < 8; ++i) wd[tid + i * 256] = ws_[tid + i * 256];
    }

    // gather neighbor mean: 16 threads per node, 16 B/lane covers the row
    {
        const int g = tid >> 4, t = tid & 15, n = nb + g;
        float acc[8] = {0, 0, 0, 0, 0, 0, 0, 0};
        const uint4* hb = (const uint4*)h_in;
        const int rp0 = row_ptr[n], rp1 = row_ptr[n + 1];
        int e = rp0;
        for (; e + 3 < rp1; e += 4) {
            const int s0 = csr_src[e], s1 = csr_src[e + 1];
            const int s2 = csr_src[e + 2], s3 = csr_src[e + 3];
            const uint4 va = hb[s0 * 16 + t];
            const uint4 vb = hb[s1 * 16 + t];
            const uint4 vc = hb[s2 * 16 + t];
            const uint4 vd = hb[s3 * 16 + t];
            acc8(acc, va); acc8(acc, vb); acc8(acc, vc); acc8(acc, vd);
        }
        for (; e < rp1; ++e) acc8(acc, hb[csr_src[e] * 16 + t]);
        const float id = inv_deg[n];
        uint4 mp;
        mp.x = packbf(acc[0] * id, acc[1] * id);
        mp.y = packbf(acc[2] * id, acc[3] * id);
        mp.z = packbf(acc[4] * id, acc[5] * id);
        mp.w = packbf(acc[6] * id, acc[7] * id);
        *(uint4*)(sMean + g * 64 + t * 4) = mp;
    }
    __syncthreads();

    const int j4 = (tid & 31) * 4;
    const int ng = tid >> 5;
    float4 a0 = {0, 0, 0, 0}, a1 = {0, 0, 0, 0};
    // pass 1: mean @ Wl^T
    #pragma unroll 4
    for (int k = 0; k < 128; k += 2) {
        const uint2 w0 = *(const uint2*)&sW[k * 64 + (j4 >> 1)];
        const uint2 w1 = *(const uint2*)&sW[(k + 1) * 64 + (j4 >> 1)];
        const float4 wa = cvt4(w0), wb = cvt4(w1);
        const u32 mu0 = sMean[ng * 64 + (k >> 1)];
        const u32 mu1 = sMean[(ng + 8) * 64 + (k >> 1)];
        const float m00 = bflo(mu0), m01 = bfhi(mu0);
        const float m10 = bflo(mu1), m11 = bfhi(mu1);
        a0.x += m00 * wa.x + m01 * wb.x; a0.y += m00 * wa.y + m01 * wb.y;
        a0.z += m00 * wa.z + m01 * wb.z; a0.w += m00 * wa.w + m01 * wb.w;
        a1.x += m10 * wa.x + m11 * wb.x; a1.y += m10 * wa.y + m11 * wb.y;
        a1.z += m10 * wa.z + m11 * wb.z; a1.w += m10 * wa.w + m11 * wb.w;
    }
    __syncthreads();
    // restage Wr
    {
        const uint4* ws_ = (const uint4*)wr_t;
        uint4* wd = (uint4*)sW;
        #pragma unroll
        for (int i = 0; i < 8; ++i) wd[tid + i * 256] = ws_[tid + i * 256];
    }
    __syncthreads();
    // pass 2: h @ Wr^T
    #pragma unroll 4
    for (int k = 0; k < 128; k += 2) {
        const uint2 w0 = *(const uint2*)&sW[k * 64 + (j4 >> 1)];
        const uint2 w1 = *(const uint2*)&sW[(k + 1) * 64 + (j4 >> 1)];
        const float4 wa = cvt4(w0), wb = cvt4(w1);
        const u32 ru0 = sRowsB[ng * 64 + (k >> 1)];
        const u32 ru1 = sRowsB[(ng + 8) * 64 + (k >> 1)];
        const float r00 = bflo(ru0), r01 = bfhi(ru0);
        const float r10 = bflo(ru1), r11 = bfhi(ru1);
        a0.x += r00 * wa.x + r01 * wb.x; a0.y += r00 * wa.y + r01 * wb.y;
        a0.z += r00 * wa.z + r01 * wb.z; a0.w += r00 * wa.w + r01 * wb.w;
        a1.x += r10 * wa.x + r11 * wb.x; a1.y += r10 * wa.y + r11 * wb.y;
        a1.z += r10 * wa.z + r11 * wb.z; a1.w += r10 * wa.w + r11 * wb.w;
    }

    // epilogue: +bias, L2 normalize, BN(eval), relu
    const float4 b = *(const float4*)(bl + j4);
    a0.x += b.x; a0.y += b.y; a0.z += b.z; a0.w += b.w;
    a1.x += b.x; a1.y += b.y; a1.z += b.z; a1.w += b.w;
    float ss0 = a0.x * a0.x + a0.y * a0.y + a0.z * a0.z + a0.w * a0.w;
    float ss1 = a1.x * a1.x + a1.y * a1.y + a1.z * a1.z + a1.w * a1.w;
    #pragma unroll
    for (int m = 16; m >= 1; m >>= 1) {
        ss0 += __shfl_xor(ss0, m);
        ss1 += __shfl_xor(ss1, m);
    }
    const float i0 = 1.0f / fmaxf(sqrtf(ss0), NORM_EPS);
    const float i1 = 1.0f / fmaxf(sqrtf(ss1), NORM_EPS);
    const float4 g = *(const float4*)(bn_g + j4);
    const float4 bb = *(const float4*)(bn_b + j4);
    const float4 mm = *(const float4*)(bn_m + j4);
    const float4 vv = *(const float4*)(bn_v + j4);
    float4 sc;
    sc.x = g.x * rsqrtf(vv.x + BN_EPS);
    sc.y = g.y * rsqrtf(vv.y + BN_EPS);
    sc.z = g.z * rsqrtf(vv.z + BN_EPS);
    sc.w = g.w * rsqrtf(vv.w + BN_EPS);
    float4 o0, o1;
    o0.x = fmaxf((a0.x * i0 - mm.x) * sc.x + bb.x, 0.f);
    o0.y = fmaxf((a0.y * i0 - mm.y) * sc.y + bb.y, 0.f);
    o0.z = fmaxf((a0.z * i0 - mm.z) * sc.z + bb.z, 0.f);
    o0.w = fmaxf((a0.w * i0 - mm.w) * sc.w + bb.w, 0.f);
    o1.x = fmaxf((a1.x * i1 - mm.x) * sc.x + bb.x, 0.f);
    o1.y = fmaxf((a1.y * i1 - mm.y) * sc.y + bb.y, 0.f);
    o1.z = fmaxf((a1.z * i1 - mm.z) * sc.z + bb.z, 0.f);
    o1.w = fmaxf((a1.w * i1 - mm.w) * sc.w + bb.w, 0.f);
    if (LAST) {
        *(float4*)(h_out_f + (size_t)(nb + ng) * 128 + j4) = o0;
        *(float4*)(h_out_f + (size_t)(nb + ng + 8) * 128 + j4) = o1;
    } else {
        uint2 p0, p1;
        p0.x = packbf(o0.x, o0.y); p0.y = packbf(o0.z, o0.w);
        p1.x = packbf(o1.x, o1.y); p1.y = packbf(o1.z, o1.w);
        *(uint2*)(h_out_bf + (size_t)(nb + ng) * 128 + j4) = p0;
        *(uint2*)(h_out_bf + (size_t)(nb + ng + 8) * 128 + j4) = p1;
    }
}

// ---------------- fused 3-head readout ----------------
__global__ __launch_bounds__(256, 4)
void heads_kernel(const float* __restrict__ h,
                  const u16* __restrict__ wt1, const float* __restrict__ b1,
                  const float* __restrict__ w2, const float* __restrict__ b2,
                  const u16* __restrict__ wtc, const float* __restrict__ cb1,
                  const float* __restrict__ cw2, const float* __restrict__ cb2,
                  const u16* __restrict__ wtb, const float* __restrict__ bb1,
                  const float* __restrict__ bw2, const float* __restrict__ bb2,
                  float* __restrict__ o_order, float* __restrict__ o_cost,
                  float* __restrict__ o_bw) {
    __shared__ u32 sW[128 * 64];
    __shared__ float sRows[TN * 128];
    const int tid = threadIdx.x;
    const int nb = blockIdx.x * TN;

    {
        const float4* s = (const float4*)(h + (size_t)nb * 128);
        float4* d = (float4*)sRows;
        d[tid] = s[tid];
        d[tid + 256] = s[tid + 256];
        const uint4* ws_ = (const uint4*)wt1;
        uint4* wd = (uint4*)sW;
        #pragma unroll
        for (int i = 0; i < 8; ++i) wd[tid + i * 256] = ws_[tid + i * 256];
    }
    __syncthreads();

    // pass 1: order head (hidden 128)
    {
        const int j4 = (tid & 31) * 4;
        const int ng = tid >> 5;
        float4 a0 = {0, 0, 0, 0}, a1 = {0, 0, 0, 0};
        #pragma unroll 4
        for (int k = 0; k < 128; k += 2) {
            const uint2 w0 = *(const uint2*)&sW[k * 64 + (j4 >> 1)];
            const uint2 w1 = *(const uint2*)&sW[(k + 1) * 64 + (j4 >> 1)];
            const float4 wa = cvt4(w0), wb = cvt4(w1);
            const float r00 = sRows[ng * 128 + k],       r01 = sRows[ng * 128 + k + 1];
            const float r10 = sRows[(ng + 8) * 128 + k], r11 = sRows[(ng + 8) * 128 + k + 1];
            a0.x += r00 * wa.x + r01 * wb.x; a0.y += r00 * wa.y + r01 * wb.y;
            a0.z += r00 * wa.z + r01 * wb.z; a0.w += r00 * wa.w + r01 * wb.w;
            a1.x += r10 * wa.x + r11 * wb.x; a1.y += r10 * wa.y + r11 * wb.y;
            a1.z += r10 * wa.z + r11 * wb.z; a1.w += r10 * wa.w + r11 * wb.w;
        }
        const float4 b = *(const float4*)(b1 + j4);
        const float4 wv = *(const float4*)(w2 + j4);
        float po0 = fmaxf(a0.x + b.x, 0.f) * wv.x + fmaxf(a0.y + b.y, 0.f) * wv.y
                  + fmaxf(a0.z + b.z, 0.f) * wv.z + fmaxf(a0.w + b.w, 0.f) * wv.w;
        float po1 = fmaxf(a1.x + b.x, 0.f) * wv.x + fmaxf(a1.y + b.y, 0.f) * wv.y
                  + fmaxf(a1.z + b.z, 0.f) * wv.z + fmaxf(a1.w + b.w, 0.f) * wv.w;
        #pragma unroll
        for (int m = 16; m >= 1; m >>= 1) {
            po0 += __shfl_xor(po0, m);
            po1 += __shfl_xor(po1, m);
        }
        if ((tid & 31) == 0) {
            const float bconst = b2[0];
            o_order[nb + ng] = po0 + bconst;
            o_order[nb + ng + 8] = po1 + bconst;
        }
    }

    // pass 2 & 3: cost / bullwhip heads (hidden 64)
    const u16* wts[2] = {wtc, wtb};
    const float* h1b[2] = {cb1, bb1};
    const float* h2w[2] = {cw2, bw2};
    const float* h2b[2] = {cb2, bb2};
    float* outs[2] = {o_cost, o_bw};
    #pragma unroll
    for (int p = 0; p < 2; ++p) {
        __syncthreads();
        {
            const uint4* ws_ = (const uint4*)wts[p];
            uint4* wd = (uint4*)sW;
            #pragma unroll
            for (int i = 0; i < 4; ++i) wd[tid + i * 256] = ws_[tid + i * 256];
        }
        __syncthreads();
        const int j4 = (tid & 15) * 4;
        const int n = tid >> 4;
        float4 a = {0, 0, 0, 0};
        #pragma unroll 4
        for (int k = 0; k < 128; k += 2) {
            const uint2 w0 = *(const uint2*)&sW[k * 32 + (j4 >> 1)];
            const uint2 w1 = *(const uint2*)&sW[(k + 1) * 32 + (j4 >> 1)];
            const float4 wa = cvt4(w0), wb = cvt4(w1);
            const float r0 = sRows[n * 128 + k], r1 = sRows[n * 128 + k + 1];
            a.x += r0 * wa.x + r1 * wb.x; a.y += r0 * wa.y + r1 * wb.y;
            a.z += r0 * wa.z + r1 * wb.z; a.w += r0 * wa.w + r1 * wb.w;
        }
        const float4 b = *(const float4*)(h1b[p] + j4);
        const float4 wv = *(const float4*)(h2w[p] + j4);
        float po = fmaxf(a.x + b.x, 0.f) * wv.x + fmaxf(a.y + b.y, 0.f) * wv.y
                 + fmaxf(a.z + b.z, 0.f) * wv.z + fmaxf(a.w + b.w, 0.f) * wv.w;
        #pragma unroll
        for (int m = 8; m >= 1; m >>= 1) po += __shfl_xor(po, m);
        if ((tid & 15) == 0) outs[p][nb + n] = po + h2b[p][0];
    }
}

extern "C" void kernel_launch(void* const* d_in, const int* in_sizes, int n_in,
                              void* d_out, int out_size, void* d_ws, size_t ws_size,
                              hipStream_t stream) {
    (void)in_sizes; (void)n_in; (void)out_size;

    const float* x       = (const float*)d_in[0];
    const int*   ei      = (const int*)d_in[1];
    const float* enc_w   = (const float*)d_in[2];
    const float* enc_b   = (const float*)d_in[3];
    const float* ll_w    = (const float*)d_in[4];
    const float* ll_b    = (const float*)d_in[5];
    const float* lr_w    = (const float*)d_in[6];
    const float* bn_g    = (const float*)d_in[7];
    const float* bn_b    = (const float*)d_in[8];
    const float* bn_m    = (const float*)d_in[9];
    const float* bn_v    = (const float*)d_in[10];
    const float* out_w1  = (const float*)d_in[11];
    const float* out_b1  = (const float*)d_in[12];
    const float* out_w2  = (const float*)d_in[13];
    const float* out_b2  = (const float*)d_in[14];
    const float* cost_w1 = (const float*)d_in[15];
    const float* cost_b1 = (const float*)d_in[16];
    const float* cost_w2 = (const float*)d_in[17];
    const float* cost_b2 = (const float*)d_in[18];
    const float* bw_w1   = (const float*)d_in[19];
    const float* bw_b1   = (const float*)d_in[20];
    const float* bw_w2   = (const float*)d_in[21];
    const float* bw_b2   = (const float*)d_in[22];

    const int* e_src = ei;
    const int* e_dst = ei + NE;

    float* o_order = (float*)d_out;
    float* o_cost  = o_order + NN;
    float* o_bw    = o_cost + NN;
    float* o_h     = o_bw + NN;   // NN*128 floats (final h, f32)

    // workspace layout
    u16* hA = (u16*)d_ws;                       // NN*128 bf16
    u16* hB = hA + (size_t)NN * 128;            // NN*128 bf16
    u16* wt = hB + (size_t)NN * 128;            // 147456 bf16
    u16* wt_enc  = wt;
    u16* wt_ll   = wt + 16384;
    u16* wt_lr   = wt + 16384 * 4;
    u16* wt_out1 = wt + 16384 * 7;
    u16* wt_c1   = wt + 16384 * 8;
    u16* wt_bw1  = wt + 16384 * 8 + 8192;
    int* cnt      = (int*)(wt + 147456);
    int* fill_cnt = cnt + NN;
    int* row_ptr  = fill_cnt + NN;              // NN+1 ints
    float* inv_deg = (float*)(row_ptr + NN + 4);
    int* csr_src  = (int*)(inv_deg + NN);
    int* blksum   = csr_src + NE;               // ~98 ints

    const size_t need = (size_t)((char*)(blksum + 256) - (char*)d_ws);
    if (ws_size < need) return;

    hipMemsetAsync(cnt, 0, 2 * NN * sizeof(int), stream);

    TposeArgs ta;
    ta.src[0] = enc_w;          ta.dst[0] = wt_enc;          ta.rows[0] = 128;
    ta.src[1] = ll_w;           ta.dst[1] = wt_ll;           ta.rows[1] = 128;
    ta.src[2] = ll_w + 16384;   ta.dst[2] = wt_ll + 16384;   ta.rows[2] = 128;
    ta.src[3] = ll_w + 32768;   ta.dst[3] = wt_ll + 32768;   ta.rows[3] = 128;
    ta.src[4] = lr_w;           ta.dst[4] = wt_lr;           ta.rows[4] = 128;
    ta.src[5] = lr_w + 16384;   ta.dst[5] = wt_lr + 16384;   ta.rows[5] = 128;
    ta.src[6] = lr_w + 32768;   ta.dst[6] = wt_lr + 32768;   ta.rows[6] = 128;
    ta.src[7] = out_w1;         ta.dst[7] = wt_out1;         ta.rows[7] = 128;
    ta.src[8] = cost_w1;        ta.dst[8] = wt_c1;           ta.rows[8] = 64;
    ta.src[9] = bw_w1;          ta.dst[9] = wt_bw1;          ta.rows[9] = 64;
    transpose_kernel<<<10, 256, 0, stream>>>(ta);

    hist_kernel<<<(NE + 255) / 256, 256, 0, stream>>>(e_dst, cnt);
    const int nblk = (NN + 1023) / 1024;
    scan1_kernel<<<nblk, 256, 0, stream>>>(cnt, row_ptr, blksum);
    scan2_kernel<<<1, 128, 0, stream>>>(blksum, nblk);
    scan3_kernel<<<(NN + 255) / 256, 256, 0, stream>>>(row_ptr, blksum, cnt, inv_deg);
    fill_kernel<<<(NE + 255) / 256, 256, 0, stream>>>(e_src, e_dst, row_ptr, fill_cnt, csr_src);

    encoder_kernel<<<NN / TN, 256, 0, stream>>>(x, hA, wt_enc, enc_b);
    sage_layer_kernel<0><<<NN / TN, 256, 0, stream>>>(hA, hB, nullptr, wt_ll, ll_b, wt_lr,
        bn_g, bn_b, bn_m, bn_v, row_ptr, csr_src, inv_deg);
    sage_layer_kernel<0><<<NN / TN, 256, 0, stream>>>(hB, hA, nullptr, wt_ll + 16384, ll_b + 128, wt_lr + 16384,
        bn_g + 128, bn_b + 128, bn_m + 128, bn_v + 128, row_ptr, csr_src, inv_deg);
    sage_layer_kernel<1><<<NN / TN, 256, 0, stream>>>(hA, nullptr, o_h, wt_ll + 32768, ll_b + 256, wt_lr + 32768,
        bn_g + 256, bn_b + 256, bn_m + 256, bn_v + 256, row_ptr, csr_src, inv_deg);
    heads_kernel<<<NN / TN, 256, 0, stream>>>(o_h, wt_out1, out_b1, out_w2, out_b2,
        wt_c1, cost_b1, cost_w2, cost_b2, wt_bw1, bw_b1, bw_w2, bw_b2,
        o_order, o_cost, o_bw);
}

// Round 3
// 437.109 us; speedup vs baseline: 3.0001x; 2.2186x over previous
//
#include <hip/hip_runtime.h>

#define NN 100000
#define NE 1600000
#define TN 16

static constexpr float BN_EPS = 1e-5f;
static constexpr float NORM_EPS = 1e-12f;

typedef unsigned int u32;
typedef unsigned short u16;
typedef __attribute__((ext_vector_type(8))) short short8;
typedef __attribute__((ext_vector_type(4))) float f32x4;

// ---------------- bf16 helpers ----------------
__device__ __forceinline__ float bflo(u32 u) {
    u32 v = u << 16; float f; __builtin_memcpy(&f, &v, 4); return f;
}
__device__ __forceinline__ float bfhi(u32 u) {
    u32 v = u & 0xffff0000u; float f; __builtin_memcpy(&f, &v, 4); return f;
}
__device__ __forceinline__ u32 packbf(float a, float b) {
    u32 ua, ub; __builtin_memcpy(&ua, &a, 4); __builtin_memcpy(&ub, &b, 4);
    u32 ra = (ua + 0x7fffu + ((ua >> 16) & 1u)) >> 16;
    u32 rb = (ub + 0x7fffu + ((ub >> 16) & 1u)) & 0xffff0000u;
    return ra | rb;
}
__device__ __forceinline__ u16 f2bf(float a) {
    u32 ua; __builtin_memcpy(&ua, &a, 4);
    return (u16)((ua + 0x7fffu + ((ua >> 16) & 1u)) >> 16);
}
__device__ __forceinline__ void acc8(float* s, uint4 v) {
    s[0] += bflo(v.x); s[1] += bfhi(v.x);
    s[2] += bflo(v.y); s[3] += bfhi(v.y);
    s[4] += bflo(v.z); s[5] += bfhi(v.z);
    s[6] += bflo(v.w); s[7] += bfhi(v.w);
}
__device__ __forceinline__ f32x4 mfma16(uint4 a, uint4 b, f32x4 c) {
    return __builtin_amdgcn_mfma_f32_16x16x32_bf16(
        __builtin_bit_cast(short8, a), __builtin_bit_cast(short8, b), c, 0, 0, 0);
}

// ------------- weight fragmentize: W[J][128] f32 -> MFMA B-frag bf16 -------
// dst[((jt*4+kk)*64 + lane)*8 + i] = bf16(W[jt*16 + (lane&15)][kk*32 + (lane>>4)*8 + i])
struct TposeArgs {
    const float* src[10];
    u16* dst[10];
    int rows[10];
};

__global__ void frag_kernel(TposeArgs a) {
    const int m = blockIdx.x;
    const float* __restrict__ s = a.src[m];
    u16* __restrict__ d = a.dst[m];
    const int total = a.rows[m] * 128;
    for (int idx = threadIdx.x; idx < total; idx += 256) {
        const int i = idx & 7;
        const int l = (idx >> 3) & 63;
        const int kk = (idx >> 9) & 3;
        const int jt = idx >> 11;
        const int j = jt * 16 + (l & 15);
        const int k = kk * 32 + ((l >> 4) << 3) + i;
        d[idx] = f2bf(s[j * 128 + k]);
    }
}

// ---------------- CSR build ----------------
__global__ void hist_kernel(const int* __restrict__ dst, int* __restrict__ cnt) {
    const int i = blockIdx.x * 256 + threadIdx.x;
    if (i < NE) atomicAdd(&cnt[dst[i]], 1);
}

__global__ void scan1_kernel(const int* __restrict__ cnt, int* __restrict__ pre,
                             int* __restrict__ blksum) {
    __shared__ int lds[256];
    const int tid = threadIdx.x;
    const int base = blockIdx.x * 1024 + tid * 4;
    const int v0 = (base + 0 < NN) ? cnt[base + 0] : 0;
    const int v1 = (base + 1 < NN) ? cnt[base + 1] : 0;
    const int v2 = (base + 2 < NN) ? cnt[base + 2] : 0;
    const int v3 = (base + 3 < NN) ? cnt[base + 3] : 0;
    const int tsum = v0 + v1 + v2 + v3;
    lds[tid] = tsum;
    __syncthreads();
    int val = tsum;
    for (int off = 1; off < 256; off <<= 1) {
        const int t = (tid >= off) ? lds[tid - off] : 0;
        __syncthreads();
        val += t;
        lds[tid] = val;
        __syncthreads();
    }
    const int excl = val - tsum;
    if (base + 0 < NN) pre[base + 0] = excl;
    if (base + 1 < NN) pre[base + 1] = excl + v0;
    if (base + 2 < NN) pre[base + 2] = excl + v0 + v1;
    if (base + 3 < NN) pre[base + 3] = excl + v0 + v1 + v2;
    if (tid == 255) blksum[blockIdx.x] = val;
}

__global__ void scan2_kernel(int* __restrict__ blksum, int nb) {
    __shared__ int lds[128];
    const int tid = threadIdx.x;
    const int v = (tid < nb) ? blksum[tid] : 0;
    lds[tid] = v;
    __syncthreads();
    int val = v;
    for (int off = 1; off < 128; off <<= 1) {
        const int t = (tid >= off) ? lds[tid - off] : 0;
        __syncthreads();
        val += t;
        lds[tid] = val;
        __syncthreads();
    }
    if (tid < nb) blksum[tid] = val - v;
}

__global__ void scan3_kernel(int* __restrict__ pre, const int* __restrict__ blksum,
                             const int* __restrict__ cnt, float* __restrict__ inv_deg) {
    const int i = blockIdx.x * 256 + threadIdx.x;
    if (i < NN) {
        pre[i] += blksum[i >> 10];
        const int c = cnt[i];
        inv_deg[i] = 1.0f / (float)(c < 1 ? 1 : c);
    }
    if (i == 0) pre[NN] = NE;
}

__global__ void fill_kernel(const int* __restrict__ src, const int* __restrict__ dst,
                            const int* __restrict__ row_ptr, int* __restrict__ fill_cnt,
                            int* __restrict__ csr_src) {
    const int i = blockIdx.x * 256 + threadIdx.x;
    if (i < NE) {
        const int d = dst[i];
        const int pos = row_ptr[d] + atomicAdd(&fill_cnt[d], 1);
        csr_src[pos] = src[i];
    }
}

// ---------------- encoder: h = relu(x @ W^T + b) via MFMA, bf16 out -------
__global__ __launch_bounds__(256, 6)
void encoder_kernel(const float* __restrict__ x, u16* __restrict__ h_out,
                    const u16* __restrict__ wfrag, const float* __restrict__ bias) {
    __shared__ uint4 sRows[256];   // 16 rows x 16 chunks (swizzled), bf16
    const int tid = threadIdx.x;
    const int nb = blockIdx.x * TN;

    {
        const int row = tid >> 4, t = tid & 15;
        const float4* xr = (const float4*)(x + (size_t)(nb + row) * 128 + t * 8);
        const float4 xa = xr[0], xb = xr[1];
        uint4 p;
        p.x = packbf(xa.x, xa.y); p.y = packbf(xa.z, xa.w);
        p.z = packbf(xb.x, xb.y); p.w = packbf(xb.z, xb.w);
        sRows[row * 16 + (t ^ (row & 7))] = p;
    }
    __syncthreads();

    const int lane = tid & 63, wave = tid >> 6;
    const int cl = lane & 15, gq = lane >> 4;
    const int jt0 = wave * 2, jt1 = wave * 2 + 1;
    const uint4* wf = (const uint4*)wfrag;
    f32x4 a0 = {0, 0, 0, 0}, a1 = {0, 0, 0, 0};
    #pragma unroll
    for (int kk = 0; kk < 4; ++kk) {
        const uint4 af = sRows[cl * 16 + ((kk * 4 + gq) ^ (cl & 7))];
        a0 = mfma16(af, wf[(jt0 * 4 + kk) * 64 + lane], a0);
        a1 = mfma16(af, wf[(jt1 * 4 + kk) * 64 + lane], a1);
    }
    const int c0 = jt0 * 16 + cl, c1 = jt1 * 16 + cl;
    const float b0 = bias[c0], b1 = bias[c1];
    #pragma unroll
    for (int r = 0; r < 4; ++r) {
        const int node = nb + gq * 4 + r;
        h_out[(size_t)node * 128 + c0] = f2bf(fmaxf(a0[r] + b0, 0.f));
        h_out[(size_t)node * 128 + c1] = f2bf(fmaxf(a1[r] + b1, 0.f));
    }
}

// ---------------- fused SAGE layer (MFMA) + optional fused heads ----------
template<int LAST>
__global__ __launch_bounds__(256, 6)
void sage_layer_kernel(const u16* __restrict__ h_in,
                       u16* __restrict__ h_out_bf, float* __restrict__ o_h,
                       const u16* __restrict__ wlfrag, const float* __restrict__ bl,
                       const u16* __restrict__ wrfrag,
                       const float* __restrict__ bn_g, const float* __restrict__ bn_b,
                       const float* __restrict__ bn_m, const float* __restrict__ bn_v,
                       const int* __restrict__ row_ptr, const int* __restrict__ csr_src,
                       const float* __restrict__ inv_deg,
                       const u16* __restrict__ o1frag, const float* __restrict__ ob1,
                       const float* __restrict__ ow2, const float* __restrict__ ob2,
                       const u16* __restrict__ c1frag, const float* __restrict__ cb1,
                       const float* __restrict__ cw2, const float* __restrict__ cb2,
                       const u16* __restrict__ b1frag, const float* __restrict__ bb1,
                       const float* __restrict__ bw2, const float* __restrict__ bb2,
                       float* __restrict__ o_order, float* __restrict__ o_cost,
                       float* __restrict__ o_bw) {
    __shared__ uint4 sRows[256];   // h rows, bf16, chunk-swizzled
    __shared__ uint4 sMean[256];   // neighbor means, bf16, chunk-swizzled
    __shared__ float ssb[4][16];
    const int tid = threadIdx.x;
    const int nb = blockIdx.x * TN;

    // stage h rows (bf16 passthrough, swizzled)
    {
        const int row = tid >> 4, t = tid & 15;
        sRows[row * 16 + (t ^ (row & 7))] = ((const uint4*)h_in)[nb * 16 + tid];
    }

    // gather neighbor mean: 16 threads per node
    {
        const int g = tid >> 4, t = tid & 15, n = nb + g;
        float acc[8] = {0, 0, 0, 0, 0, 0, 0, 0};
        const uint4* hb = (const uint4*)h_in;
        const int rp0 = row_ptr[n], rp1 = row_ptr[n + 1];
        int e = rp0;
        for (; e + 3 < rp1; e += 4) {
            const int s0 = csr_src[e], s1 = csr_src[e + 1];
            const int s2 = csr_src[e + 2], s3 = csr_src[e + 3];
            const uint4 va = hb[s0 * 16 + t];
            const uint4 vb = hb[s1 * 16 + t];
            const uint4 vc = hb[s2 * 16 + t];
            const uint4 vd = hb[s3 * 16 + t];
            acc8(acc, va); acc8(acc, vb); acc8(acc, vc); acc8(acc, vd);
        }
        for (; e < rp1; ++e) acc8(acc, hb[csr_src[e] * 16 + t]);
        const float id = inv_deg[n];
        uint4 mp;
        mp.x = packbf(acc[0] * id, acc[1] * id);
        mp.y = packbf(acc[2] * id, acc[3] * id);
        mp.z = packbf(acc[4] * id, acc[5] * id);
        mp.w = packbf(acc[6] * id, acc[7] * id);
        sMean[g * 16 + (t ^ (g & 7))] = mp;
    }
    __syncthreads();

    const int lane = tid & 63, wave = tid >> 6;
    const int cl = lane & 15, gq = lane >> 4;
    const int jt0 = wave * 2, jt1 = wave * 2 + 1;
    f32x4 a0 = {0, 0, 0, 0}, a1 = {0, 0, 0, 0};
    // pass 1: mean @ Wl^T   pass 2: h @ Wr^T  (same accumulators)
    {
        const uint4* wf = (const uint4*)wlfrag;
        #pragma unroll
        for (int kk = 0; kk < 4; ++kk) {
            const uint4 af = sMean[cl * 16 + ((kk * 4 + gq) ^ (cl & 7))];
            a0 = mfma16(af, wf[(jt0 * 4 + kk) * 64 + lane], a0);
            a1 = mfma16(af, wf[(jt1 * 4 + kk) * 64 + lane], a1);
        }
    }
    {
        const uint4* wf = (const uint4*)wrfrag;
        #pragma unroll
        for (int kk = 0; kk < 4; ++kk) {
            const uint4 af = sRows[cl * 16 + ((kk * 4 + gq) ^ (cl & 7))];
            a0 = mfma16(af, wf[(jt0 * 4 + kk) * 64 + lane], a0);
            a1 = mfma16(af, wf[(jt1 * 4 + kk) * 64 + lane], a1);
        }
    }

    // epilogue: +bias, row L2-norm (cross-wave), BN(eval), relu
    const int c0 = jt0 * 16 + cl, c1 = jt1 * 16 + cl;
    const float bl0 = bl[c0], bl1 = bl[c1];
    float t0[4], t1[4], ss[4];
    #pragma unroll
    for (int r = 0; r < 4; ++r) {
        t0[r] = a0[r] + bl0;
        t1[r] = a1[r] + bl1;
        ss[r] = t0[r] * t0[r] + t1[r] * t1[r];
    }
    #pragma unroll
    for (int m = 1; m <= 8; m <<= 1) {
        ss[0] += __shfl_xor(ss[0], m);
        ss[1] += __shfl_xor(ss[1], m);
        ss[2] += __shfl_xor(ss[2], m);
        ss[3] += __shfl_xor(ss[3], m);
    }
    if (cl == 0) {
        ssb[wave][gq * 4 + 0] = ss[0];
        ssb[wave][gq * 4 + 1] = ss[1];
        ssb[wave][gq * 4 + 2] = ss[2];
        ssb[wave][gq * 4 + 3] = ss[3];
    }
    __syncthreads();

    const float sc0 = bn_g[c0] * rsqrtf(bn_v[c0] + BN_EPS);
    const float sc1 = bn_g[c1] * rsqrtf(bn_v[c1] + BN_EPS);
    const float m0 = bn_m[c0], m1 = bn_m[c1];
    const float bb0 = bn_b[c0], bb1v = bn_b[c1];
    float f0[4], f1[4];
    #pragma unroll
    for (int r = 0; r < 4; ++r) {
        const int rw = gq * 4 + r;
        const float tot = ssb[0][rw] + ssb[1][rw] + ssb[2][rw] + ssb[3][rw];
        const float inv = 1.0f / fmaxf(sqrtf(tot), NORM_EPS);
        f0[r] = fmaxf((t0[r] * inv - m0) * sc0 + bb0, 0.f);
        f1[r] = fmaxf((t1[r] * inv - m1) * sc1 + bb1v, 0.f);
    }

    if (!LAST) {
        #pragma unroll
        for (int r = 0; r < 4; ++r) {
            const size_t node = nb + gq * 4 + r;
            h_out_bf[node * 128 + c0] = f2bf(f0[r]);
            h_out_bf[node * 128 + c1] = f2bf(f1[r]);
        }
        return;
    }

    // LAST: write f32 h output + restage bf16 h into sRows for fused heads
    #pragma unroll
    for (int r = 0; r < 4; ++r) {
        const size_t node = nb + gq * 4 + r;
        o_h[node * 128 + c0] = f0[r];
        o_h[node * 128 + c1] = f1[r];
    }
    u16* sr16 = (u16*)sRows;
    #pragma unroll
    for (int r = 0; r < 4; ++r) {
        const int rw = gq * 4 + r;
        sr16[rw * 128 + (((c0 >> 3) ^ (rw & 7)) << 3) + (c0 & 7)] = f2bf(f0[r]);
        sr16[rw * 128 + (((c1 >> 3) ^ (rw & 7)) << 3) + (c1 & 7)] = f2bf(f1[r]);
    }
    __syncthreads();

    // ---- order head: hidden 128, then dot with ow2 ----
    {
        const uint4* wf = (const uint4*)o1frag;
        f32x4 h0 = {0, 0, 0, 0}, h1 = {0, 0, 0, 0};
        #pragma unroll
        for (int kk = 0; kk < 4; ++kk) {
            const uint4 af = sRows[cl * 16 + ((kk * 4 + gq) ^ (cl & 7))];
            h0 = mfma16(af, wf[(jt0 * 4 + kk) * 64 + lane], h0);
            h1 = mfma16(af, wf[(jt1 * 4 + kk) * 64 + lane], h1);
        }
        const float hb0 = ob1[c0], hb1 = ob1[c1];
        const float w20 = ow2[c0], w21 = ow2[c1];
        float p[4];
        #pragma unroll
        for (int r = 0; r < 4; ++r)
            p[r] = fmaxf(h0[r] + hb0, 0.f) * w20 + fmaxf(h1[r] + hb1, 0.f) * w21;
        #pragma unroll
        for (int m = 1; m <= 8; m <<= 1) {
            p[0] += __shfl_xor(p[0], m); p[1] += __shfl_xor(p[1], m);
            p[2] += __shfl_xor(p[2], m); p[3] += __shfl_xor(p[3], m);
        }
        if (cl == 0) {
            #pragma unroll
            for (int r = 0; r < 4; ++r) ssb[wave][gq * 4 + r] = p[r];
        }
        __syncthreads();
        if (tid < 16)
            o_order[nb + tid] = ssb[0][tid] + ssb[1][tid] + ssb[2][tid] + ssb[3][tid] + ob2[0];
        __syncthreads();
    }

    // ---- cost / bullwhip heads: hidden 64 (one jt tile per wave) ----
    const u16* hfr[2] = {c1frag, b1frag};
    const float* hb1a[2] = {cb1, bb1};
    const float* hw2a[2] = {cw2, bw2};
    const float* hb2a[2] = {cb2, bb2};
    float* outs[2] = {o_cost, o_bw};
    #pragma unroll
    for (int ph = 0; ph < 2; ++ph) {
        const uint4* wf = (const uint4*)hfr[ph];
        f32x4 h0 = {0, 0, 0, 0};
        #pragma unroll
        for (int kk = 0; kk < 4; ++kk) {
            const uint4 af = sRows[cl * 16 + ((kk * 4 + gq) ^ (cl & 7))];
            h0 = mfma16(af, wf[(wave * 4 + kk) * 64 + lane], h0);
        }
        const int cc = wave * 16 + cl;
        const float hb = hb1a[ph][cc], w2 = hw2a[ph][cc];
        float p[4];
        #pragma unroll
        for (int r = 0; r < 4; ++r) p[r] = fmaxf(h0[r] + hb, 0.f) * w2;
        #pragma unroll
        for (int m = 1; m <= 8; m <<= 1) {
            p[0] += __shfl_xor(p[0], m); p[1] += __shfl_xor(p[1], m);
            p[2] += __shfl_xor(p[2], m); p[3] += __shfl_xor(p[3], m);
        }
        if (cl == 0) {
            #pragma unroll
            for (int r = 0; r < 4; ++r) ssb[wave][gq * 4 + r] = p[r];
        }
        __syncthreads();
        if (tid < 16)
            outs[ph][nb + tid] = ssb[0][tid] + ssb[1][tid] + ssb[2][tid] + ssb[3][tid] + hb2a[ph][0];
        __syncthreads();
    }
}

extern "C" void kernel_launch(void* const* d_in, const int* in_sizes, int n_in,
                              void* d_out, int out_size, void* d_ws, size_t ws_size,
                              hipStream_t stream) {
    (void)in_sizes; (void)n_in; (void)out_size;

    const float* x       = (const float*)d_in[0];
    const int*   ei      = (const int*)d_in[1];
    const float* enc_w   = (const float*)d_in[2];
    const float* enc_b   = (const float*)d_in[3];
    const float* ll_w    = (const float*)d_in[4];
    const float* ll_b    = (const float*)d_in[5];
    const float* lr_w    = (const float*)d_in[6];
    const float* bn_g    = (const float*)d_in[7];
    const float* bn_b    = (const float*)d_in[8];
    const float* bn_m    = (const float*)d_in[9];
    const float* bn_v    = (const float*)d_in[10];
    const float* out_w1  = (const float*)d_in[11];
    const float* out_b1  = (const float*)d_in[12];
    const float* out_w2  = (const float*)d_in[13];
    const float* out_b2  = (const float*)d_in[14];
    const float* cost_w1 = (const float*)d_in[15];
    const float* cost_b1 = (const float*)d_in[16];
    const float* cost_w2 = (const float*)d_in[17];
    const float* cost_b2 = (const float*)d_in[18];
    const float* bw_w1   = (const float*)d_in[19];
    const float* bw_b1   = (const float*)d_in[20];
    const float* bw_w2   = (const float*)d_in[21];
    const float* bw_b2   = (const float*)d_in[22];

    const int* e_src = ei;
    const int* e_dst = ei + NE;

    float* o_order = (float*)d_out;
    float* o_cost  = o_order + NN;
    float* o_bw    = o_cost + NN;
    float* o_h     = o_bw + NN;   // NN*128 f32 (final h)

    // workspace layout
    u16* hA = (u16*)d_ws;                       // NN*128 bf16
    u16* hB = hA + (size_t)NN * 128;            // NN*128 bf16
    u16* wt = hB + (size_t)NN * 128;            // 147456 bf16 (fragment layout)
    u16* wt_enc  = wt;
    u16* wt_ll   = wt + 16384;
    u16* wt_lr   = wt + 16384 * 4;
    u16* wt_out1 = wt + 16384 * 7;
    u16* wt_c1   = wt + 16384 * 8;
    u16* wt_bw1  = wt + 16384 * 8 + 8192;
    int* cnt      = (int*)(wt + 147456);
    int* fill_cnt = cnt + NN;
    int* row_ptr  = fill_cnt + NN;              // NN+1 ints
    float* inv_deg = (float*)(row_ptr + NN + 4);
    int* csr_src  = (int*)(inv_deg + NN);
    int* blksum   = csr_src + NE;               // ~98 ints

    const size_t need = (size_t)((char*)(blksum + 256) - (char*)d_ws);
    if (ws_size < need) return;

    hipMemsetAsync(cnt, 0, 2 * NN * sizeof(int), stream);

    TposeArgs ta;
    ta.src[0] = enc_w;          ta.dst[0] = wt_enc;          ta.rows[0] = 128;
    ta.src[1] = ll_w;           ta.dst[1] = wt_ll;           ta.rows[1] = 128;
    ta.src[2] = ll_w + 16384;   ta.dst[2] = wt_ll + 16384;   ta.rows[2] = 128;
    ta.src[3] = ll_w + 32768;   ta.dst[3] = wt_ll + 32768;   ta.rows[3] = 128;
    ta.src[4] = lr_w;           ta.dst[4] = wt_lr;           ta.rows[4] = 128;
    ta.src[5] = lr_w + 16384;   ta.dst[5] = wt_lr + 16384;   ta.rows[5] = 128;
    ta.src[6] = lr_w + 32768;   ta.dst[6] = wt_lr + 32768;   ta.rows[6] = 128;
    ta.src[7] = out_w1;         ta.dst[7] = wt_out1;         ta.rows[7] = 128;
    ta.src[8] = cost_w1;        ta.dst[8] = wt_c1;           ta.rows[8] = 64;
    ta.src[9] = bw_w1;          ta.dst[9] = wt_bw1;          ta.rows[9] = 64;
    frag_kernel<<<10, 256, 0, stream>>>(ta);

    hist_kernel<<<(NE + 255) / 256, 256, 0, stream>>>(e_dst, cnt);
    const int nblk = (NN + 1023) / 1024;
    scan1_kernel<<<nblk, 256, 0, stream>>>(cnt, row_ptr, blksum);
    scan2_kernel<<<1, 128, 0, stream>>>(blksum, nblk);
    scan3_kernel<<<(NN + 255) / 256, 256, 0, stream>>>(row_ptr, blksum, cnt, inv_deg);
    fill_kernel<<<(NE + 255) / 256, 256, 0, stream>>>(e_src, e_dst, row_ptr, fill_cnt, csr_src);

    encoder_kernel<<<NN / TN, 256, 0, stream>>>(x, hA, wt_enc, enc_b);
    sage_layer_kernel<0><<<NN / TN, 256, 0, stream>>>(hA, hB, nullptr, wt_ll, ll_b, wt_lr,
        bn_g, bn_b, bn_m, bn_v, row_ptr, csr_src, inv_deg,
        nullptr, nullptr, nullptr, nullptr, nullptr, nullptr, nullptr, nullptr,
        nullptr, nullptr, nullptr, nullptr, nullptr, nullptr, nullptr);
    sage_layer_kernel<0><<<NN / TN, 256, 0, stream>>>(hB, hA, nullptr, wt_ll + 16384, ll_b + 128, wt_lr + 16384,
        bn_g + 128, bn_b + 128, bn_m + 128, bn_v + 128, row_ptr, csr_src, inv_deg,
        nullptr, nullptr, nullptr, nullptr, nullptr, nullptr, nullptr, nullptr,
        nullptr, nullptr, nullptr, nullptr, nullptr, nullptr, nullptr);
    sage_layer_kernel<1><<<NN / TN, 256, 0, stream>>>(hA, nullptr, o_h, wt_ll + 32768, ll_b + 256, wt_lr + 32768,
        bn_g + 256, bn_b + 256, bn_m + 256, bn_v + 256, row_ptr, csr_src, inv_deg,
        wt_out1, out_b1, out_w2, out_b2,
        wt_c1, cost_b1, cost_w2, cost_b2,
        wt_bw1, bw_b1, bw_w2, bw_b2,
        o_order, o_cost, o_bw);
}

// Round 4
// 314.881 us; speedup vs baseline: 4.1646x; 1.3882x over previous
//
#include <hip/hip_runtime.h>

#define NN 100000
#define NE 1600000
#define TN 16
#define NBK 391      // ceil(NN/256) buckets of 256 nodes
#define BCAP 5120    // per-bucket edge capacity (mean 4096, sigma 64)
#define CTILE 8192   // edges per workgroup in bucket_scatter

static constexpr float BN_EPS = 1e-5f;
static constexpr float NORM_EPS = 1e-12f;

typedef unsigned int u32;
typedef unsigned short u16;
typedef __attribute__((ext_vector_type(8))) short short8;
typedef __attribute__((ext_vector_type(4))) float f32x4;

// ---------------- bf16 helpers ----------------
__device__ __forceinline__ float bflo(u32 u) {
    u32 v = u << 16; float f; __builtin_memcpy(&f, &v, 4); return f;
}
__device__ __forceinline__ float bfhi(u32 u) {
    u32 v = u & 0xffff0000u; float f; __builtin_memcpy(&f, &v, 4); return f;
}
__device__ __forceinline__ u32 packbf(float a, float b) {
    u32 ua, ub; __builtin_memcpy(&ua, &a, 4); __builtin_memcpy(&ub, &b, 4);
    u32 ra = (ua + 0x7fffu + ((ua >> 16) & 1u)) >> 16;
    u32 rb = (ub + 0x7fffu + ((ub >> 16) & 1u)) & 0xffff0000u;
    return ra | rb;
}
__device__ __forceinline__ u16 f2bf(float a) {
    u32 ua; __builtin_memcpy(&ua, &a, 4);
    return (u16)((ua + 0x7fffu + ((ua >> 16) & 1u)) >> 16);
}
__device__ __forceinline__ void acc8(float* s, uint4 v) {
    s[0] += bflo(v.x); s[1] += bfhi(v.x);
    s[2] += bflo(v.y); s[3] += bfhi(v.y);
    s[4] += bflo(v.z); s[5] += bfhi(v.z);
    s[6] += bflo(v.w); s[7] += bfhi(v.w);
}
__device__ __forceinline__ f32x4 mfma16(uint4 a, uint4 b, f32x4 c) {
    return __builtin_amdgcn_mfma_f32_16x16x32_bf16(
        __builtin_bit_cast(short8, a), __builtin_bit_cast(short8, b), c, 0, 0, 0);
}

// ------------- weight fragmentize: W[J][128] f32 -> MFMA B-frag bf16 -------
struct TposeArgs {
    const float* src[10];
    u16* dst[10];
    int rows[10];
};

__global__ void frag_kernel(TposeArgs a) {
    const int m = blockIdx.x;
    const float* __restrict__ s = a.src[m];
    u16* __restrict__ d = a.dst[m];
    const int total = a.rows[m] * 128;
    for (int idx = threadIdx.x; idx < total; idx += 256) {
        const int i = idx & 7;
        const int l = (idx >> 3) & 63;
        const int kk = (idx >> 9) & 3;
        const int jt = idx >> 11;
        const int j = jt * 16 + (l & 15);
        const int k = kk * 32 + ((l >> 4) << 3) + i;
        d[idx] = f2bf(s[j * 128 + k]);
    }
}

// ---------------- CSR build: bucketed, LDS-amortized ----------------
// Phase C: scatter edges into fixed-capacity bucket regions.
__global__ __launch_bounds__(256, 4)
void bucket_scatter_kernel(const int* __restrict__ e_src, const int* __restrict__ e_dst,
                           int* __restrict__ bcnt, u32* __restrict__ ebuf) {
    __shared__ int h[NBK];
    const int tid = threadIdx.x;
    const int base = blockIdx.x * CTILE;
    const int end = (base + CTILE < NE) ? base + CTILE : NE;
    for (int i = tid; i < NBK; i += 256) h[i] = 0;
    __syncthreads();
    for (int e = base + tid; e < end; e += 256)
        atomicAdd(&h[e_dst[e] >> 8], 1);
    __syncthreads();
    for (int i = tid; i < NBK; i += 256) {
        const int c = h[i];
        h[i] = (c > 0) ? atomicAdd(&bcnt[i], c) : 0;
    }
    __syncthreads();
    for (int e = base + tid; e < end; e += 256) {
        const int d = e_dst[e];
        const int b = d >> 8;
        const int slot = atomicAdd(&h[b], 1);
        if (slot < BCAP)
            ebuf[(size_t)b * BCAP + slot] = (u32)e_src[e] | ((u32)(d & 255) << 17);
    }
}

// Phase B: 1-wave exclusive scan of bucket counts -> bucket bases.
__global__ void bscan_kernel(const int* __restrict__ bcnt, int* __restrict__ bbase) {
    const int lane = threadIdx.x;   // 64 threads
    const int per = (NBK + 63) / 64;  // 7
    int vals[8];
    int s = 0;
    for (int i = 0; i < per; ++i) {
        const int idx = lane * per + i;
        const int v = (idx < NBK) ? bcnt[idx] : 0;
        vals[i] = s; s += v;
    }
    int incl = s;
    for (int off = 1; off < 64; off <<= 1) {
        const int t = __shfl_up(incl, off);
        if (lane >= off) incl += t;
    }
    const int excl = incl - s;
    for (int i = 0; i < per; ++i) {
        const int idx = lane * per + i;
        if (idx < NBK) bbase[idx] = excl + vals[i];
    }
    if (lane == 63) bbase[NBK] = excl + s;
}

// Phase D: per-bucket CSR finalize (row_ptr, inv_deg, csr_src).
__global__ __launch_bounds__(256, 4)
void csr_finalize_kernel(const u32* __restrict__ ebuf, const int* __restrict__ bcnt,
                         const int* __restrict__ bbase,
                         int* __restrict__ row_ptr, float* __restrict__ inv_deg,
                         int* __restrict__ csr_src) {
    __shared__ int cnt[256];
    __shared__ int rc[256];
    const int b = blockIdx.x;
    const int tid = threadIdx.x;
    const int n0 = b << 8;
    const int nb_nodes = (NN - n0 < 256) ? NN - n0 : 256;
    int ecnt = bcnt[b];
    if (ecnt > BCAP) ecnt = BCAP;
    const int gbase = bbase[b];
    const u32* eb = ebuf + (size_t)b * BCAP;
    cnt[tid] = 0;
    __syncthreads();
    for (int e = tid; e < ecnt; e += 256)
        atomicAdd(&cnt[eb[e] >> 17], 1);
    __syncthreads();
    const int myc = cnt[tid];
    int val = myc;
    for (int off = 1; off < 256; off <<= 1) {
        const int t = (tid >= off) ? cnt[tid - off] : 0;
        __syncthreads();
        val += t;
        cnt[tid] = val;
        __syncthreads();
    }
    const int excl = val - myc;
    if (tid < nb_nodes) {
        row_ptr[n0 + tid] = gbase + excl;
        inv_deg[n0 + tid] = 1.0f / (float)(myc < 1 ? 1 : myc);
    }
    rc[tid] = gbase + excl;
    __syncthreads();
    for (int e = tid; e < ecnt; e += 256) {
        const u32 p = eb[e];
        const int pos = atomicAdd(&rc[p >> 17], 1);
        csr_src[pos] = (int)(p & 0x1FFFFu);
    }
    if (b == NBK - 1 && tid == 0) row_ptr[NN] = NE;
}

// ---------------- encoder: h = relu(x @ W^T + b) via MFMA, bf16 out -------
__global__ __launch_bounds__(256, 6)
void encoder_kernel(const float* __restrict__ x, u16* __restrict__ h_out,
                    const u16* __restrict__ wfrag, const float* __restrict__ bias) {
    __shared__ uint4 sRows[256];
    const int tid = threadIdx.x;
    const int nb = blockIdx.x * TN;

    {
        const int row = tid >> 4, t = tid & 15;
        const float4* xr = (const float4*)(x + (size_t)(nb + row) * 128 + t * 8);
        const float4 xa = xr[0], xb = xr[1];
        uint4 p;
        p.x = packbf(xa.x, xa.y); p.y = packbf(xa.z, xa.w);
        p.z = packbf(xb.x, xb.y); p.w = packbf(xb.z, xb.w);
        sRows[row * 16 + (t ^ (row & 7))] = p;
    }
    __syncthreads();

    const int lane = tid & 63, wave = tid >> 6;
    const int cl = lane & 15, gq = lane >> 4;
    const int jt0 = wave * 2, jt1 = wave * 2 + 1;
    const uint4* wf = (const uint4*)wfrag;
    f32x4 a0 = {0, 0, 0, 0}, a1 = {0, 0, 0, 0};
    #pragma unroll
    for (int kk = 0; kk < 4; ++kk) {
        const uint4 af = sRows[cl * 16 + ((kk * 4 + gq) ^ (cl & 7))];
        a0 = mfma16(af, wf[(jt0 * 4 + kk) * 64 + lane], a0);
        a1 = mfma16(af, wf[(jt1 * 4 + kk) * 64 + lane], a1);
    }
    const int c0 = jt0 * 16 + cl, c1 = jt1 * 16 + cl;
    const float b0 = bias[c0], b1 = bias[c1];
    #pragma unroll
    for (int r = 0; r < 4; ++r) {
        const int node = nb + gq * 4 + r;
        h_out[(size_t)node * 128 + c0] = f2bf(fmaxf(a0[r] + b0, 0.f));
        h_out[(size_t)node * 128 + c1] = f2bf(fmaxf(a1[r] + b1, 0.f));
    }
}

// ---------------- fused SAGE layer (MFMA) + optional fused heads ----------
template<int LAST>
__global__ __launch_bounds__(256, 6)
void sage_layer_kernel(const u16* __restrict__ h_in,
                       u16* __restrict__ h_out_bf, float* __restrict__ o_h,
                       const u16* __restrict__ wlfrag, const float* __restrict__ bl,
                       const u16* __restrict__ wrfrag,
                       const float* __restrict__ bn_g, const float* __restrict__ bn_b,
                       const float* __restrict__ bn_m, const float* __restrict__ bn_v,
                       const int* __restrict__ row_ptr, const int* __restrict__ csr_src,
                       const float* __restrict__ inv_deg,
                       const u16* __restrict__ o1frag, const float* __restrict__ ob1,
                       const float* __restrict__ ow2, const float* __restrict__ ob2,
                       const u16* __restrict__ c1frag, const float* __restrict__ cb1,
                       const float* __restrict__ cw2, const float* __restrict__ cb2,
                       const u16* __restrict__ b1frag, const float* __restrict__ bb1,
                       const float* __restrict__ bw2, const float* __restrict__ bb2,
                       float* __restrict__ o_order, float* __restrict__ o_cost,
                       float* __restrict__ o_bw) {
    __shared__ uint4 sRows[256];
    __shared__ uint4 sMean[256];
    __shared__ float ssb[4][16];
    const int tid = threadIdx.x;
    const int nb = blockIdx.x * TN;

    {
        const int row = tid >> 4, t = tid & 15;
        sRows[row * 16 + (t ^ (row & 7))] = ((const uint4*)h_in)[nb * 16 + tid];
    }

    {
        const int g = tid >> 4, t = tid & 15, n = nb + g;
        float acc[8] = {0, 0, 0, 0, 0, 0, 0, 0};
        const uint4* hb = (const uint4*)h_in;
        const int rp0 = row_ptr[n], rp1 = row_ptr[n + 1];
        int e = rp0;
        for (; e + 3 < rp1; e += 4) {
            const int s0 = csr_src[e], s1 = csr_src[e + 1];
            const int s2 = csr_src[e + 2], s3 = csr_src[e + 3];
            const uint4 va = hb[s0 * 16 + t];
            const uint4 vb = hb[s1 * 16 + t];
            const uint4 vc = hb[s2 * 16 + t];
            const uint4 vd = hb[s3 * 16 + t];
            acc8(acc, va); acc8(acc, vb); acc8(acc, vc); acc8(acc, vd);
        }
        for (; e < rp1; ++e) acc8(acc, hb[csr_src[e] * 16 + t]);
        const float id = inv_deg[n];
        uint4 mp;
        mp.x = packbf(acc[0] * id, acc[1] * id);
        mp.y = packbf(acc[2] * id, acc[3] * id);
        mp.z = packbf(acc[4] * id, acc[5] * id);
        mp.w = packbf(acc[6] * id, acc[7] * id);
        sMean[g * 16 + (t ^ (g & 7))] = mp;
    }
    __syncthreads();

    const int lane = tid & 63, wave = tid >> 6;
    const int cl = lane & 15, gq = lane >> 4;
    const int jt0 = wave * 2, jt1 = wave * 2 + 1;
    f32x4 a0 = {0, 0, 0, 0}, a1 = {0, 0, 0, 0};
    {
        const uint4* wf = (const uint4*)wlfrag;
        #pragma unroll
        for (int kk = 0; kk < 4; ++kk) {
            const uint4 af = sMean[cl * 16 + ((kk * 4 + gq) ^ (cl & 7))];
            a0 = mfma16(af, wf[(jt0 * 4 + kk) * 64 + lane], a0);
            a1 = mfma16(af, wf[(jt1 * 4 + kk) * 64 + lane], a1);
        }
    }
    {
        const uint4* wf = (const uint4*)wrfrag;
        #pragma unroll
        for (int kk = 0; kk < 4; ++kk) {
            const uint4 af = sRows[cl * 16 + ((kk * 4 + gq) ^ (cl & 7))];
            a0 = mfma16(af, wf[(jt0 * 4 + kk) * 64 + lane], a0);
            a1 = mfma16(af, wf[(jt1 * 4 + kk) * 64 + lane], a1);
        }
    }

    const int c0 = jt0 * 16 + cl, c1 = jt1 * 16 + cl;
    const float bl0 = bl[c0], bl1 = bl[c1];
    float t0[4], t1[4], ss[4];
    #pragma unroll
    for (int r = 0; r < 4; ++r) {
        t0[r] = a0[r] + bl0;
        t1[r] = a1[r] + bl1;
        ss[r] = t0[r] * t0[r] + t1[r] * t1[r];
    }
    #pragma unroll
    for (int m = 1; m <= 8; m <<= 1) {
        ss[0] += __shfl_xor(ss[0], m);
        ss[1] += __shfl_xor(ss[1], m);
        ss[2] += __shfl_xor(ss[2], m);
        ss[3] += __shfl_xor(ss[3], m);
    }
    if (cl == 0) {
        ssb[wave][gq * 4 + 0] = ss[0];
        ssb[wave][gq * 4 + 1] = ss[1];
        ssb[wave][gq * 4 + 2] = ss[2];
        ssb[wave][gq * 4 + 3] = ss[3];
    }
    __syncthreads();

    const float sc0 = bn_g[c0] * rsqrtf(bn_v[c0] + BN_EPS);
    const float sc1 = bn_g[c1] * rsqrtf(bn_v[c1] + BN_EPS);
    const float m0 = bn_m[c0], m1 = bn_m[c1];
    const float bb0 = bn_b[c0], bb1v = bn_b[c1];
    float f0[4], f1[4];
    #pragma unroll
    for (int r = 0; r < 4; ++r) {
        const int rw = gq * 4 + r;
        const float tot = ssb[0][rw] + ssb[1][rw] + ssb[2][rw] + ssb[3][rw];
        const float inv = 1.0f / fmaxf(sqrtf(tot), NORM_EPS);
        f0[r] = fmaxf((t0[r] * inv - m0) * sc0 + bb0, 0.f);
        f1[r] = fmaxf((t1[r] * inv - m1) * sc1 + bb1v, 0.f);
    }

    if (!LAST) {
        #pragma unroll
        for (int r = 0; r < 4; ++r) {
            const size_t node = nb + gq * 4 + r;
            h_out_bf[node * 128 + c0] = f2bf(f0[r]);
            h_out_bf[node * 128 + c1] = f2bf(f1[r]);
        }
        return;
    }

    #pragma unroll
    for (int r = 0; r < 4; ++r) {
        const size_t node = nb + gq * 4 + r;
        o_h[node * 128 + c0] = f0[r];
        o_h[node * 128 + c1] = f1[r];
    }
    u16* sr16 = (u16*)sRows;
    #pragma unroll
    for (int r = 0; r < 4; ++r) {
        const int rw = gq * 4 + r;
        sr16[rw * 128 + (((c0 >> 3) ^ (rw & 7)) << 3) + (c0 & 7)] = f2bf(f0[r]);
        sr16[rw * 128 + (((c1 >> 3) ^ (rw & 7)) << 3) + (c1 & 7)] = f2bf(f1[r]);
    }
    __syncthreads();

    {
        const uint4* wf = (const uint4*)o1frag;
        f32x4 h0 = {0, 0, 0, 0}, h1 = {0, 0, 0, 0};
        #pragma unroll
        for (int kk = 0; kk < 4; ++kk) {
            const uint4 af = sRows[cl * 16 + ((kk * 4 + gq) ^ (cl & 7))];
            h0 = mfma16(af, wf[(jt0 * 4 + kk) * 64 + lane], h0);
            h1 = mfma16(af, wf[(jt1 * 4 + kk) * 64 + lane], h1);
        }
        const float hb0 = ob1[c0], hb1 = ob1[c1];
        const float w20 = ow2[c0], w21 = ow2[c1];
        float p[4];
        #pragma unroll
        for (int r = 0; r < 4; ++r)
            p[r] = fmaxf(h0[r] + hb0, 0.f) * w20 + fmaxf(h1[r] + hb1, 0.f) * w21;
        #pragma unroll
        for (int m = 1; m <= 8; m <<= 1) {
            p[0] += __shfl_xor(p[0], m); p[1] += __shfl_xor(p[1], m);
            p[2] += __shfl_xor(p[2], m); p[3] += __shfl_xor(p[3], m);
        }
        if (cl == 0) {
            #pragma unroll
            for (int r = 0; r < 4; ++r) ssb[wave][gq * 4 + r] = p[r];
        }
        __syncthreads();
        if (tid < 16)
            o_order[nb + tid] = ssb[0][tid] + ssb[1][tid] + ssb[2][tid] + ssb[3][tid] + ob2[0];
        __syncthreads();
    }

    const u16* hfr[2] = {c1frag, b1frag};
    const float* hb1a[2] = {cb1, bb1};
    const float* hw2a[2] = {cw2, bw2};
    const float* hb2a[2] = {cb2, bb2};
    float* outs[2] = {o_cost, o_bw};
    #pragma unroll
    for (int ph = 0; ph < 2; ++ph) {
        const uint4* wf = (const uint4*)hfr[ph];
        f32x4 h0 = {0, 0, 0, 0};
        #pragma unroll
        for (int kk = 0; kk < 4; ++kk) {
            const uint4 af = sRows[cl * 16 + ((kk * 4 + gq) ^ (cl & 7))];
            h0 = mfma16(af, wf[(wave * 4 + kk) * 64 + lane], h0);
        }
        const int cc = wave * 16 + cl;
        const float hb = hb1a[ph][cc], w2 = hw2a[ph][cc];
        float p[4];
        #pragma unroll
        for (int r = 0; r < 4; ++r) p[r] = fmaxf(h0[r] + hb, 0.f) * w2;
        #pragma unroll
        for (int m = 1; m <= 8; m <<= 1) {
            p[0] += __shfl_xor(p[0], m); p[1] += __shfl_xor(p[1], m);
            p[2] += __shfl_xor(p[2], m); p[3] += __shfl_xor(p[3], m);
        }
        if (cl == 0) {
            #pragma unroll
            for (int r = 0; r < 4; ++r) ssb[wave][gq * 4 + r] = p[r];
        }
        __syncthreads();
        if (tid < 16)
            outs[ph][nb + tid] = ssb[0][tid] + ssb[1][tid] + ssb[2][tid] + ssb[3][tid] + hb2a[ph][0];
        __syncthreads();
    }
}

extern "C" void kernel_launch(void* const* d_in, const int* in_sizes, int n_in,
                              void* d_out, int out_size, void* d_ws, size_t ws_size,
                              hipStream_t stream) {
    (void)in_sizes; (void)n_in; (void)out_size;

    const float* x       = (const float*)d_in[0];
    const int*   ei      = (const int*)d_in[1];
    const float* enc_w   = (const float*)d_in[2];
    const float* enc_b   = (const float*)d_in[3];
    const float* ll_w    = (const float*)d_in[4];
    const float* ll_b    = (const float*)d_in[5];
    const float* lr_w    = (const float*)d_in[6];
    const float* bn_g    = (const float*)d_in[7];
    const float* bn_b    = (const float*)d_in[8];
    const float* bn_m    = (const float*)d_in[9];
    const float* bn_v    = (const float*)d_in[10];
    const float* out_w1  = (const float*)d_in[11];
    const float* out_b1  = (const float*)d_in[12];
    const float* out_w2  = (const float*)d_in[13];
    const float* out_b2  = (const float*)d_in[14];
    const float* cost_w1 = (const float*)d_in[15];
    const float* cost_b1 = (const float*)d_in[16];
    const float* cost_w2 = (const float*)d_in[17];
    const float* cost_b2 = (const float*)d_in[18];
    const float* bw_w1   = (const float*)d_in[19];
    const float* bw_b1   = (const float*)d_in[20];
    const float* bw_w2   = (const float*)d_in[21];
    const float* bw_b2   = (const float*)d_in[22];

    const int* e_src = ei;
    const int* e_dst = ei + NE;

    float* o_order = (float*)d_out;
    float* o_cost  = o_order + NN;
    float* o_bw    = o_cost + NN;
    float* o_h     = o_bw + NN;   // NN*128 f32 (final h)

    // workspace layout
    u16* hA = (u16*)d_ws;                       // NN*128 bf16
    u16* hB = hA + (size_t)NN * 128;            // NN*128 bf16
    u16* wt = hB + (size_t)NN * 128;            // 147456 bf16 (fragment layout)
    u16* wt_enc  = wt;
    u16* wt_ll   = wt + 16384;
    u16* wt_lr   = wt + 16384 * 4;
    u16* wt_out1 = wt + 16384 * 7;
    u16* wt_c1   = wt + 16384 * 8;
    u16* wt_bw1  = wt + 16384 * 8 + 8192;
    int* row_ptr  = (int*)(wt + 147456);        // NN+1 (+pad)
    float* inv_deg = (float*)(row_ptr + NN + 4);
    int* csr_src  = (int*)(inv_deg + NN);       // NE
    int* bcnt     = csr_src + NE;               // NBK+1
    int* bbase    = bcnt + NBK + 1;             // NBK+1
    u32* ebuf     = (u32*)(bbase + NBK + 1);    // NBK*BCAP

    const size_t need = (size_t)((char*)(ebuf + (size_t)NBK * BCAP) - (char*)d_ws);
    if (ws_size < need) return;

    hipMemsetAsync(bcnt, 0, (NBK + 1) * sizeof(int), stream);

    TposeArgs ta;
    ta.src[0] = enc_w;          ta.dst[0] = wt_enc;          ta.rows[0] = 128;
    ta.src[1] = ll_w;           ta.dst[1] = wt_ll;           ta.rows[1] = 128;
    ta.src[2] = ll_w + 16384;   ta.dst[2] = wt_ll + 16384;   ta.rows[2] = 128;
    ta.src[3] = ll_w + 32768;   ta.dst[3] = wt_ll + 32768;   ta.rows[3] = 128;
    ta.src[4] = lr_w;           ta.dst[4] = wt_lr;           ta.rows[4] = 128;
    ta.src[5] = lr_w + 16384;   ta.dst[5] = wt_lr + 16384;   ta.rows[5] = 128;
    ta.src[6] = lr_w + 32768;   ta.dst[6] = wt_lr + 32768;   ta.rows[6] = 128;
    ta.src[7] = out_w1;         ta.dst[7] = wt_out1;         ta.rows[7] = 128;
    ta.src[8] = cost_w1;        ta.dst[8] = wt_c1;           ta.rows[8] = 64;
    ta.src[9] = bw_w1;          ta.dst[9] = wt_bw1;          ta.rows[9] = 64;
    frag_kernel<<<10, 256, 0, stream>>>(ta);

    bucket_scatter_kernel<<<(NE + CTILE - 1) / CTILE, 256, 0, stream>>>(e_src, e_dst, bcnt, ebuf);
    bscan_kernel<<<1, 64, 0, stream>>>(bcnt, bbase);
    csr_finalize_kernel<<<NBK, 256, 0, stream>>>(ebuf, bcnt, bbase, row_ptr, inv_deg, csr_src);

    encoder_kernel<<<NN / TN, 256, 0, stream>>>(x, hA, wt_enc, enc_b);
    sage_layer_kernel<0><<<NN / TN, 256, 0, stream>>>(hA, hB, nullptr, wt_ll, ll_b, wt_lr,
        bn_g, bn_b, bn_m, bn_v, row_ptr, csr_src, inv_deg,
        nullptr, nullptr, nullptr, nullptr, nullptr, nullptr, nullptr, nullptr,
        nullptr, nullptr, nullptr, nullptr, nullptr, nullptr, nullptr);
    sage_layer_kernel<0><<<NN / TN, 256, 0, stream>>>(hB, hA, nullptr, wt_ll + 16384, ll_b + 128, wt_lr + 16384,
        bn_g + 128, bn_b + 128, bn_m + 128, bn_v + 128, row_ptr, csr_src, inv_deg,
        nullptr, nullptr, nullptr, nullptr, nullptr, nullptr, nullptr, nullptr,
        nullptr, nullptr, nullptr, nullptr, nullptr, nullptr, nullptr);
    sage_layer_kernel<1><<<NN / TN, 256, 0, stream>>>(hA, nullptr, o_h, wt_ll + 32768, ll_b + 256, wt_lr + 32768,
        bn_g + 256, bn_b + 256, bn_m + 256, bn_v + 256, row_ptr, csr_src, inv_deg,
        wt_out1, out_b1, out_w2, out_b2,
        wt_c1, cost_b1, cost_w2, cost_b2,
        wt_bw1, bw_b1, bw_w2, bw_b2,
        o_order, o_cost, o_bw);
}

// Round 5
// 312.155 us; speedup vs baseline: 4.2010x; 1.0087x over previous
//
#include <hip/hip_runtime.h>

#define NN 100000
#define NE 1600000
#define TN 16        // encoder tile
#define TNL 32       // sage-layer tile
#define NBK 391      // ceil(NN/256) buckets of 256 nodes
#define BCAP 5120    // per-bucket edge capacity (mean 4096)
#define CTILE 8192   // edges per workgroup in bucket_scatter

static constexpr float BN_EPS = 1e-5f;
static constexpr float NORM_EPS = 1e-12f;

typedef unsigned int u32;
typedef unsigned short u16;
typedef __attribute__((ext_vector_type(8))) short short8;
typedef __attribute__((ext_vector_type(4))) float f32x4;

// ---------------- bf16 helpers ----------------
__device__ __forceinline__ float bflo(u32 u) {
    u32 v = u << 16; float f; __builtin_memcpy(&f, &v, 4); return f;
}
__device__ __forceinline__ float bfhi(u32 u) {
    u32 v = u & 0xffff0000u; float f; __builtin_memcpy(&f, &v, 4); return f;
}
__device__ __forceinline__ u32 packbf(float a, float b) {
    u32 ua, ub; __builtin_memcpy(&ua, &a, 4); __builtin_memcpy(&ub, &b, 4);
    u32 ra = (ua + 0x7fffu + ((ua >> 16) & 1u)) >> 16;
    u32 rb = (ub + 0x7fffu + ((ub >> 16) & 1u)) & 0xffff0000u;
    return ra | rb;
}
__device__ __forceinline__ u16 f2bf(float a) {
    u32 ua; __builtin_memcpy(&ua, &a, 4);
    return (u16)((ua + 0x7fffu + ((ua >> 16) & 1u)) >> 16);
}
__device__ __forceinline__ void acc8(float* s, uint4 v) {
    s[0] += bflo(v.x); s[1] += bfhi(v.x);
    s[2] += bflo(v.y); s[3] += bfhi(v.y);
    s[4] += bflo(v.z); s[5] += bfhi(v.z);
    s[6] += bflo(v.w); s[7] += bfhi(v.w);
}
__device__ __forceinline__ f32x4 mfma16(uint4 a, uint4 b, f32x4 c) {
    return __builtin_amdgcn_mfma_f32_16x16x32_bf16(
        __builtin_bit_cast(short8, a), __builtin_bit_cast(short8, b), c, 0, 0, 0);
}

// ------------- weight fragmentize: W[J][128] f32 -> MFMA B-frag bf16 -------
struct TposeArgs {
    const float* src[10];
    u16* dst[10];
    int rows[10];
};

__global__ void frag_kernel(TposeArgs a) {
    const int m = blockIdx.x;
    const float* __restrict__ s = a.src[m];
    u16* __restrict__ d = a.dst[m];
    const int total = a.rows[m] * 128;
    for (int idx = threadIdx.x; idx < total; idx += 256) {
        const int i = idx & 7;
        const int l = (idx >> 3) & 63;
        const int kk = (idx >> 9) & 3;
        const int jt = idx >> 11;
        const int j = jt * 16 + (l & 15);
        const int k = kk * 32 + ((l >> 4) << 3) + i;
        d[idx] = f2bf(s[j * 128 + k]);
    }
}

// ---------------- CSR build: bucketed, LDS-amortized ----------------
__global__ __launch_bounds__(256, 4)
void bucket_scatter_kernel(const int* __restrict__ e_src, const int* __restrict__ e_dst,
                           int* __restrict__ bcnt, u32* __restrict__ ebuf) {
    __shared__ int h[NBK];
    const int tid = threadIdx.x;
    const int base = blockIdx.x * CTILE;
    const int end = (base + CTILE < NE) ? base + CTILE : NE;
    for (int i = tid; i < NBK; i += 256) h[i] = 0;
    __syncthreads();
    for (int e = base + tid; e < end; e += 256)
        atomicAdd(&h[e_dst[e] >> 8], 1);
    __syncthreads();
    for (int i = tid; i < NBK; i += 256) {
        const int c = h[i];
        h[i] = (c > 0) ? atomicAdd(&bcnt[i], c) : 0;
    }
    __syncthreads();
    for (int e = base + tid; e < end; e += 256) {
        const int d = e_dst[e];
        const int b = d >> 8;
        const int slot = atomicAdd(&h[b], 1);
        if (slot < BCAP)
            ebuf[(size_t)b * BCAP + slot] = (u32)e_src[e] | ((u32)(d & 255) << 17);
    }
}

__global__ void bscan_kernel(const int* __restrict__ bcnt, int* __restrict__ bbase) {
    const int lane = threadIdx.x;   // 64 threads
    const int per = (NBK + 63) / 64;
    int vals[8];
    int s = 0;
    for (int i = 0; i < per; ++i) {
        const int idx = lane * per + i;
        const int v = (idx < NBK) ? bcnt[idx] : 0;
        vals[i] = s; s += v;
    }
    int incl = s;
    for (int off = 1; off < 64; off <<= 1) {
        const int t = __shfl_up(incl, off);
        if (lane >= off) incl += t;
    }
    const int excl = incl - s;
    for (int i = 0; i < per; ++i) {
        const int idx = lane * per + i;
        if (idx < NBK) bbase[idx] = excl + vals[i];
    }
    if (lane == 63) bbase[NBK] = excl + s;
}

__global__ __launch_bounds__(256, 4)
void csr_finalize_kernel(const u32* __restrict__ ebuf, const int* __restrict__ bcnt,
                         const int* __restrict__ bbase,
                         int* __restrict__ row_ptr, float* __restrict__ inv_deg,
                         int* __restrict__ csr_src) {
    __shared__ int cnt[256];
    __shared__ int rc[256];
    const int b = blockIdx.x;
    const int tid = threadIdx.x;
    const int n0 = b << 8;
    const int nb_nodes = (NN - n0 < 256) ? NN - n0 : 256;
    int ecnt = bcnt[b];
    if (ecnt > BCAP) ecnt = BCAP;
    const int gbase = bbase[b];
    const u32* eb = ebuf + (size_t)b * BCAP;
    cnt[tid] = 0;
    __syncthreads();
    for (int e = tid; e < ecnt; e += 256)
        atomicAdd(&cnt[eb[e] >> 17], 1);
    __syncthreads();
    const int myc = cnt[tid];
    int val = myc;
    for (int off = 1; off < 256; off <<= 1) {
        const int t = (tid >= off) ? cnt[tid - off] : 0;
        __syncthreads();
        val += t;
        cnt[tid] = val;
        __syncthreads();
    }
    const int excl = val - myc;
    if (tid < nb_nodes) {
        row_ptr[n0 + tid] = gbase + excl;
        inv_deg[n0 + tid] = 1.0f / (float)(myc < 1 ? 1 : myc);
    }
    rc[tid] = gbase + excl;
    __syncthreads();
    for (int e = tid; e < ecnt; e += 256) {
        const u32 p = eb[e];
        const int pos = atomicAdd(&rc[p >> 17], 1);
        csr_src[pos] = (int)(p & 0x1FFFFu);
    }
    if (b == NBK - 1 && tid == 0) row_ptr[NN] = NE;
}

// ---------------- encoder: h = relu(x @ W^T + b) via MFMA, bf16 out -------
__global__ __launch_bounds__(256, 6)
void encoder_kernel(const float* __restrict__ x, u16* __restrict__ h_out,
                    const u16* __restrict__ wfrag, const float* __restrict__ bias) {
    __shared__ uint4 sRows[256];
    const int tid = threadIdx.x;
    const int nb = blockIdx.x * TN;

    {
        const int row = tid >> 4, t = tid & 15;
        const float4* xr = (const float4*)(x + (size_t)(nb + row) * 128 + t * 8);
        const float4 xa = xr[0], xb = xr[1];
        uint4 p;
        p.x = packbf(xa.x, xa.y); p.y = packbf(xa.z, xa.w);
        p.z = packbf(xb.x, xb.y); p.w = packbf(xb.z, xb.w);
        sRows[row * 16 + (t ^ (row & 7))] = p;
    }
    __syncthreads();

    const int lane = tid & 63, wave = tid >> 6;
    const int cl = lane & 15, gq = lane >> 4;
    const int jt0 = wave * 2, jt1 = wave * 2 + 1;
    const uint4* wf = (const uint4*)wfrag;
    f32x4 a0 = {0, 0, 0, 0}, a1 = {0, 0, 0, 0};
    #pragma unroll
    for (int kk = 0; kk < 4; ++kk) {
        const uint4 af = sRows[cl * 16 + ((kk * 4 + gq) ^ (cl & 7))];
        a0 = mfma16(af, wf[(jt0 * 4 + kk) * 64 + lane], a0);
        a1 = mfma16(af, wf[(jt1 * 4 + kk) * 64 + lane], a1);
    }
    const int c0 = jt0 * 16 + cl, c1 = jt1 * 16 + cl;
    const float b0 = bias[c0], b1 = bias[c1];
    #pragma unroll
    for (int r = 0; r < 4; ++r) {
        const int node = nb + gq * 4 + r;
        h_out[(size_t)node * 128 + c0] = f2bf(fmaxf(a0[r] + b0, 0.f));
        h_out[(size_t)node * 128 + c1] = f2bf(fmaxf(a1[r] + b1, 0.f));
    }
}

// ---------------- fused SAGE layer (MFMA, TNL=32) + optional fused heads --
template<int LAST>
__global__ __launch_bounds__(256, 8)
void sage_layer_kernel(const u16* __restrict__ h_in,
                       u16* __restrict__ h_out_bf, float* __restrict__ o_h,
                       const u16* __restrict__ wlfrag, const float* __restrict__ bl,
                       const u16* __restrict__ wrfrag,
                       const float* __restrict__ bn_g, const float* __restrict__ bn_b,
                       const float* __restrict__ bn_m, const float* __restrict__ bn_v,
                       const int* __restrict__ row_ptr, const int* __restrict__ csr_src,
                       const float* __restrict__ inv_deg,
                       const u16* __restrict__ o1frag, const float* __restrict__ ob1,
                       const float* __restrict__ ow2, const float* __restrict__ ob2,
                       const u16* __restrict__ c1frag, const float* __restrict__ cb1,
                       const float* __restrict__ cw2, const float* __restrict__ cb2,
                       const u16* __restrict__ b1frag, const float* __restrict__ bb1,
                       const float* __restrict__ bw2, const float* __restrict__ bb2,
                       float* __restrict__ o_order, float* __restrict__ o_cost,
                       float* __restrict__ o_bw) {
    __shared__ uint4 sRows[512];   // 32 rows x 16 chunks, swizzled
    __shared__ uint4 sMean[512];
    __shared__ float ssb[4][32];
    const int tid = threadIdx.x;
    const int nb = blockIdx.x * TNL;

    // stage h rows (bf16 passthrough, swizzled): 512 uint4
    {
        const uint4* src = (const uint4*)h_in + (size_t)nb * 16;
        const int i0 = tid, i1 = tid + 256;
        sRows[(i0 >> 4) * 16 + ((i0 & 15) ^ ((i0 >> 4) & 7))] = src[i0];
        sRows[(i1 >> 4) * 16 + ((i1 & 15) ^ ((i1 >> 4) & 7))] = src[i1];
    }

    // gather neighbor mean: 16-lane group serves 2 nodes (g, g+16)
    {
        const int g = tid >> 4, t = tid & 15;
        const uint4* hb = (const uint4*)h_in;
        #pragma unroll
        for (int half = 0; half < 2; ++half) {
            const int row = g + half * 16;
            const int n = nb + row;
            float acc[8] = {0, 0, 0, 0, 0, 0, 0, 0};
            const int rp0 = row_ptr[n], rp1 = row_ptr[n + 1];
            int e = rp0;
            for (; e + 3 < rp1; e += 4) {
                const int s0 = csr_src[e], s1 = csr_src[e + 1];
                const int s2 = csr_src[e + 2], s3 = csr_src[e + 3];
                const uint4 va = hb[s0 * 16 + t];
                const uint4 vb = hb[s1 * 16 + t];
                const uint4 vc = hb[s2 * 16 + t];
                const uint4 vd = hb[s3 * 16 + t];
                acc8(acc, va); acc8(acc, vb); acc8(acc, vc); acc8(acc, vd);
            }
            for (; e < rp1; ++e) acc8(acc, hb[csr_src[e] * 16 + t]);
            const float id = inv_deg[n];
            uint4 mp;
            mp.x = packbf(acc[0] * id, acc[1] * id);
            mp.y = packbf(acc[2] * id, acc[3] * id);
            mp.z = packbf(acc[4] * id, acc[5] * id);
            mp.w = packbf(acc[6] * id, acc[7] * id);
            sMean[row * 16 + (t ^ (row & 7))] = mp;
        }
    }
    __syncthreads();

    const int lane = tid & 63, wave = tid >> 6;
    const int cl = lane & 15, gq = lane >> 4;
    const int jt0 = wave * 2, jt1 = wave * 2 + 1;
    f32x4 a00 = {0,0,0,0}, a01 = {0,0,0,0}, a10 = {0,0,0,0}, a11 = {0,0,0,0};
    {
        const uint4* wf = (const uint4*)wlfrag;
        #pragma unroll
        for (int kk = 0; kk < 4; ++kk) {
            const int ch = (kk * 4 + gq) ^ (cl & 7);
            const uint4 af0 = sMean[cl * 16 + ch];
            const uint4 af1 = sMean[(16 + cl) * 16 + ch];
            const uint4 b0 = wf[(jt0 * 4 + kk) * 64 + lane];
            const uint4 b1 = wf[(jt1 * 4 + kk) * 64 + lane];
            a00 = mfma16(af0, b0, a00); a01 = mfma16(af0, b1, a01);
            a10 = mfma16(af1, b0, a10); a11 = mfma16(af1, b1, a11);
        }
    }
    {
        const uint4* wf = (const uint4*)wrfrag;
        #pragma unroll
        for (int kk = 0; kk < 4; ++kk) {
            const int ch = (kk * 4 + gq) ^ (cl & 7);
            const uint4 af0 = sRows[cl * 16 + ch];
            const uint4 af1 = sRows[(16 + cl) * 16 + ch];
            const uint4 b0 = wf[(jt0 * 4 + kk) * 64 + lane];
            const uint4 b1 = wf[(jt1 * 4 + kk) * 64 + lane];
            a00 = mfma16(af0, b0, a00); a01 = mfma16(af0, b1, a01);
            a10 = mfma16(af1, b0, a10); a11 = mfma16(af1, b1, a11);
        }
    }

    // epilogue: +bias, row L2-norm (cross-wave), BN(eval), relu
    const int c0 = jt0 * 16 + cl, c1 = jt1 * 16 + cl;
    const float bl0 = bl[c0], bl1 = bl[c1];
    float t00[4], t01[4], t10[4], t11[4], ss0[4], ss1[4];
    #pragma unroll
    for (int r = 0; r < 4; ++r) {
        t00[r] = a00[r] + bl0; t01[r] = a01[r] + bl1;
        t10[r] = a10[r] + bl0; t11[r] = a11[r] + bl1;
        ss0[r] = t00[r] * t00[r] + t01[r] * t01[r];
        ss1[r] = t10[r] * t10[r] + t11[r] * t11[r];
    }
    #pragma unroll
    for (int m = 1; m <= 8; m <<= 1) {
        #pragma unroll
        for (int r = 0; r < 4; ++r) {
            ss0[r] += __shfl_xor(ss0[r], m);
            ss1[r] += __shfl_xor(ss1[r], m);
        }
    }
    if (cl == 0) {
        #pragma unroll
        for (int r = 0; r < 4; ++r) {
            ssb[wave][gq * 4 + r] = ss0[r];
            ssb[wave][16 + gq * 4 + r] = ss1[r];
        }
    }
    __syncthreads();

    const float sc0 = bn_g[c0] * rsqrtf(bn_v[c0] + BN_EPS);
    const float sc1 = bn_g[c1] * rsqrtf(bn_v[c1] + BN_EPS);
    const float m0 = bn_m[c0], m1 = bn_m[c1];
    const float bb0 = bn_b[c0], bb1v = bn_b[c1];
    float f00[4], f01[4], f10[4], f11[4];
    #pragma unroll
    for (int r = 0; r < 4; ++r) {
        const int rw0 = gq * 4 + r, rw1 = 16 + rw0;
        const float tot0 = ssb[0][rw0] + ssb[1][rw0] + ssb[2][rw0] + ssb[3][rw0];
        const float tot1 = ssb[0][rw1] + ssb[1][rw1] + ssb[2][rw1] + ssb[3][rw1];
        const float inv0 = 1.0f / fmaxf(sqrtf(tot0), NORM_EPS);
        const float inv1 = 1.0f / fmaxf(sqrtf(tot1), NORM_EPS);
        f00[r] = fmaxf((t00[r] * inv0 - m0) * sc0 + bb0, 0.f);
        f01[r] = fmaxf((t01[r] * inv0 - m1) * sc1 + bb1v, 0.f);
        f10[r] = fmaxf((t10[r] * inv1 - m0) * sc0 + bb0, 0.f);
        f11[r] = fmaxf((t11[r] * inv1 - m1) * sc1 + bb1v, 0.f);
    }

    if (!LAST) {
        #pragma unroll
        for (int r = 0; r < 4; ++r) {
            const size_t n0s = nb + gq * 4 + r;
            const size_t n1s = n0s + 16;
            h_out_bf[n0s * 128 + c0] = f2bf(f00[r]);
            h_out_bf[n0s * 128 + c1] = f2bf(f01[r]);
            h_out_bf[n1s * 128 + c0] = f2bf(f10[r]);
            h_out_bf[n1s * 128 + c1] = f2bf(f11[r]);
        }
        return;
    }

    // LAST: write f32 h + restage bf16 h into sRows for fused heads
    u16* sr16 = (u16*)sRows;
    #pragma unroll
    for (int r = 0; r < 4; ++r) {
        const int rw0 = gq * 4 + r, rw1 = 16 + rw0;
        const size_t n0s = nb + rw0, n1s = nb + rw1;
        o_h[n0s * 128 + c0] = f00[r];
        o_h[n0s * 128 + c1] = f01[r];
        o_h[n1s * 128 + c0] = f10[r];
        o_h[n1s * 128 + c1] = f11[r];
        sr16[rw0 * 128 + (((c0 >> 3) ^ (rw0 & 7)) << 3) + (c0 & 7)] = f2bf(f00[r]);
        sr16[rw0 * 128 + (((c1 >> 3) ^ (rw0 & 7)) << 3) + (c1 & 7)] = f2bf(f01[r]);
        sr16[rw1 * 128 + (((c0 >> 3) ^ (rw1 & 7)) << 3) + (c0 & 7)] = f2bf(f10[r]);
        sr16[rw1 * 128 + (((c1 >> 3) ^ (rw1 & 7)) << 3) + (c1 & 7)] = f2bf(f11[r]);
    }
    __syncthreads();

    // ---- order head: hidden 128, then dot with ow2 ----
    {
        const uint4* wf = (const uint4*)o1frag;
        f32x4 h00 = {0,0,0,0}, h01 = {0,0,0,0}, h10 = {0,0,0,0}, h11 = {0,0,0,0};
        #pragma unroll
        for (int kk = 0; kk < 4; ++kk) {
            const int ch = (kk * 4 + gq) ^ (cl & 7);
            const uint4 af0 = sRows[cl * 16 + ch];
            const uint4 af1 = sRows[(16 + cl) * 16 + ch];
            const uint4 b0 = wf[(jt0 * 4 + kk) * 64 + lane];
            const uint4 b1 = wf[(jt1 * 4 + kk) * 64 + lane];
            h00 = mfma16(af0, b0, h00); h01 = mfma16(af0, b1, h01);
            h10 = mfma16(af1, b0, h10); h11 = mfma16(af1, b1, h11);
        }
        const float hb0 = ob1[c0], hb1 = ob1[c1];
        const float w20 = ow2[c0], w21 = ow2[c1];
        float p0[4], p1[4];
        #pragma unroll
        for (int r = 0; r < 4; ++r) {
            p0[r] = fmaxf(h00[r] + hb0, 0.f) * w20 + fmaxf(h01[r] + hb1, 0.f) * w21;
            p1[r] = fmaxf(h10[r] + hb0, 0.f) * w20 + fmaxf(h11[r] + hb1, 0.f) * w21;
        }
        #pragma unroll
        for (int m = 1; m <= 8; m <<= 1) {
            #pragma unroll
            for (int r = 0; r < 4; ++r) {
                p0[r] += __shfl_xor(p0[r], m);
                p1[r] += __shfl_xor(p1[r], m);
            }
        }
        if (cl == 0) {
            #pragma unroll
            for (int r = 0; r < 4; ++r) {
                ssb[wave][gq * 4 + r] = p0[r];
                ssb[wave][16 + gq * 4 + r] = p1[r];
            }
        }
        __syncthreads();
        if (tid < 32)
            o_order[nb + tid] = ssb[0][tid] + ssb[1][tid] + ssb[2][tid] + ssb[3][tid] + ob2[0];
        __syncthreads();
    }

    // ---- cost / bullwhip heads: hidden 64 (one 16-col tile per wave) ----
    const u16* hfr[2] = {c1frag, b1frag};
    const float* hb1a[2] = {cb1, bb1};
    const float* hw2a[2] = {cw2, bw2};
    const float* hb2a[2] = {cb2, bb2};
    float* outs[2] = {o_cost, o_bw};
    #pragma unroll
    for (int ph = 0; ph < 2; ++ph) {
        const uint4* wf = (const uint4*)hfr[ph];
        f32x4 g0 = {0,0,0,0}, g1 = {0,0,0,0};
        #pragma unroll
        for (int kk = 0; kk < 4; ++kk) {
            const int ch = (kk * 4 + gq) ^ (cl & 7);
            const uint4 af0 = sRows[cl * 16 + ch];
            const uint4 af1 = sRows[(16 + cl) * 16 + ch];
            const uint4 b = wf[(wave * 4 + kk) * 64 + lane];
            g0 = mfma16(af0, b, g0);
            g1 = mfma16(af1, b, g1);
        }
        const int cc = wave * 16 + cl;
        const float hb = hb1a[ph][cc], w2 = hw2a[ph][cc];
        float p0[4], p1[4];
        #pragma unroll
        for (int r = 0; r < 4; ++r) {
            p0[r] = fmaxf(g0[r] + hb, 0.f) * w2;
            p1[r] = fmaxf(g1[r] + hb, 0.f) * w2;
        }
        #pragma unroll
        for (int m = 1; m <= 8; m <<= 1) {
            #pragma unroll
            for (int r = 0; r < 4; ++r) {
                p0[r] += __shfl_xor(p0[r], m);
                p1[r] += __shfl_xor(p1[r], m);
            }
        }
        if (cl == 0) {
            #pragma unroll
            for (int r = 0; r < 4; ++r) {
                ssb[wave][gq * 4 + r] = p0[r];
                ssb[wave][16 + gq * 4 + r] = p1[r];
            }
        }
        __syncthreads();
        if (tid < 32)
            outs[ph][nb + tid] = ssb[0][tid] + ssb[1][tid] + ssb[2][tid] + ssb[3][tid] + hb2a[ph][0];
        __syncthreads();
    }
}

extern "C" void kernel_launch(void* const* d_in, const int* in_sizes, int n_in,
                              void* d_out, int out_size, void* d_ws, size_t ws_size,
                              hipStream_t stream) {
    (void)in_sizes; (void)n_in; (void)out_size;

    const float* x       = (const float*)d_in[0];
    const int*   ei      = (const int*)d_in[1];
    const float* enc_w   = (const float*)d_in[2];
    const float* enc_b   = (const float*)d_in[3];
    const float* ll_w    = (const float*)d_in[4];
    const float* ll_b    = (const float*)d_in[5];
    const float* lr_w    = (const float*)d_in[6];
    const float* bn_g    = (const float*)d_in[7];
    const float* bn_b    = (const float*)d_in[8];
    const float* bn_m    = (const float*)d_in[9];
    const float* bn_v    = (const float*)d_in[10];
    const float* out_w1  = (const float*)d_in[11];
    const float* out_b1  = (const float*)d_in[12];
    const float* out_w2  = (const float*)d_in[13];
    const float* out_b2  = (const float*)d_in[14];
    const float* cost_w1 = (const float*)d_in[15];
    const float* cost_b1 = (const float*)d_in[16];
    const float* cost_w2 = (const float*)d_in[17];
    const float* cost_b2 = (const float*)d_in[18];
    const float* bw_w1   = (const float*)d_in[19];
    const float* bw_b1   = (const float*)d_in[20];
    const float* bw_w2   = (const float*)d_in[21];
    const float* bw_b2   = (const float*)d_in[22];

    const int* e_src = ei;
    const int* e_dst = ei + NE;

    float* o_order = (float*)d_out;
    float* o_cost  = o_order + NN;
    float* o_bw    = o_cost + NN;
    float* o_h     = o_bw + NN;   // NN*128 f32 (final h)

    // workspace layout
    u16* hA = (u16*)d_ws;                       // NN*128 bf16
    u16* hB = hA + (size_t)NN * 128;            // NN*128 bf16
    u16* wt = hB + (size_t)NN * 128;            // 147456 bf16 (fragment layout)
    u16* wt_enc  = wt;
    u16* wt_ll   = wt + 16384;
    u16* wt_lr   = wt + 16384 * 4;
    u16* wt_out1 = wt + 16384 * 7;
    u16* wt_c1   = wt + 16384 * 8;
    u16* wt_bw1  = wt + 16384 * 8 + 8192;
    int* row_ptr  = (int*)(wt + 147456);        // NN+1 (+pad)
    float* inv_deg = (float*)(row_ptr + NN + 4);
    int* csr_src  = (int*)(inv_deg + NN);       // NE
    int* bcnt     = csr_src + NE;               // NBK+1
    int* bbase    = bcnt + NBK + 1;             // NBK+1
    u32* ebuf     = (u32*)(bbase + NBK + 1);    // NBK*BCAP

    const size_t need = (size_t)((char*)(ebuf + (size_t)NBK * BCAP) - (char*)d_ws);
    if (ws_size < need) return;

    hipMemsetAsync(bcnt, 0, (NBK + 1) * sizeof(int), stream);

    TposeArgs ta;
    ta.src[0] = enc_w;          ta.dst[0] = wt_enc;          ta.rows[0] = 128;
    ta.src[1] = ll_w;           ta.dst[1] = wt_ll;           ta.rows[1] = 128;
    ta.src[2] = ll_w + 16384;   ta.dst[2] = wt_ll + 16384;   ta.rows[2] = 128;
    ta.src[3] = ll_w + 32768;   ta.dst[3] = wt_ll + 32768;   ta.rows[3] = 128;
    ta.src[4] = lr_w;           ta.dst[4] = wt_lr;           ta.rows[4] = 128;
    ta.src[5] = lr_w + 16384;   ta.dst[5] = wt_lr + 16384;   ta.rows[5] = 128;
    ta.src[6] = lr_w + 32768;   ta.dst[6] = wt_lr + 32768;   ta.rows[6] = 128;
    ta.src[7] = out_w1;         ta.dst[7] = wt_out1;         ta.rows[7] = 128;
    ta.src[8] = cost_w1;        ta.dst[8] = wt_c1;           ta.rows[8] = 64;
    ta.src[9] = bw_w1;          ta.dst[9] = wt_bw1;          ta.rows[9] = 64;
    frag_kernel<<<10, 256, 0, stream>>>(ta);

    bucket_scatter_kernel<<<(NE + CTILE - 1) / CTILE, 256, 0, stream>>>(e_src, e_dst, bcnt, ebuf);
    bscan_kernel<<<1, 64, 0, stream>>>(bcnt, bbase);
    csr_finalize_kernel<<<NBK, 256, 0, stream>>>(ebuf, bcnt, bbase, row_ptr, inv_deg, csr_src);

    encoder_kernel<<<NN / TN, 256, 0, stream>>>(x, hA, wt_enc, enc_b);
    sage_layer_kernel<0><<<NN / TNL, 256, 0, stream>>>(hA, hB, nullptr, wt_ll, ll_b, wt_lr,
        bn_g, bn_b, bn_m, bn_v, row_ptr, csr_src, inv_deg,
        nullptr, nullptr, nullptr, nullptr, nullptr, nullptr, nullptr, nullptr,
        nullptr, nullptr, nullptr, nullptr, nullptr, nullptr, nullptr);
    sage_layer_kernel<0><<<NN / TNL, 256, 0, stream>>>(hB, hA, nullptr, wt_ll + 16384, ll_b + 128, wt_lr + 16384,
        bn_g + 128, bn_b + 128, bn_m + 128, bn_v + 128, row_ptr, csr_src, inv_deg,
        nullptr, nullptr, nullptr, nullptr, nullptr, nullptr, nullptr, nullptr,
        nullptr, nullptr, nullptr, nullptr, nullptr, nullptr, nullptr);
    sage_layer_kernel<1><<<NN / TNL, 256, 0, stream>>>(hA, nullptr, o_h, wt_ll + 32768, ll_b + 256, wt_lr + 32768,
        bn_g + 256, bn_b + 256, bn_m + 256, bn_v + 256, row_ptr, csr_src, inv_deg,
        wt_out1, out_b1, out_w2, out_b2,
        wt_c1, cost_b1, cost_w2, cost_b2,
        wt_bw1, bw_b1, bw_w2, bw_b2,
        o_order, o_cost, o_bw);
}